// Round 6
// baseline (294.829 us; speedup 1.0000x reference)
//
#include <hip/hip_runtime.h>
#include <hip/hip_bf16.h>
#include <math.h>

typedef __bf16 bf16_t;
typedef __bf16 bf16x4 __attribute__((ext_vector_type(4)));
typedef __bf16 bf16x8 __attribute__((ext_vector_type(8)));
typedef float  f32x4  __attribute__((ext_vector_type(4)));

#define NTOK 16384   // B*S
#define HD   256     // hidden
#define TD   768
#define ID   1024
#define NPAIR 32768  // NTOK*2 per branch
#define MOE_TPB 264  // 128-row tiles per branch (256 + 8 boundary)
#define FLAG_CAP 4096

__device__ inline float gelu_f(float x){
    return 0.5f * x * (1.0f + erff(x * 0.70710678118654752f));
}
__device__ inline bf16x4 cvt4(float4 a){
    bf16x4 o; o[0]=(bf16_t)a.x; o[1]=(bf16_t)a.y; o[2]=(bf16_t)a.z; o[3]=(bf16_t)a.w; return o;
}
__device__ inline f32x4 mfma16(bf16x8 a, bf16x8 b, f32x4 c){
    return __builtin_amdgcn_mfma_f32_16x16x32_bf16(a, b, c, 0, 0, 0);
}
// async global->LDS, 16B per lane; lds dest = wave-uniform base + lane*16
__device__ inline void gload_lds16(const void* g, void* l){
    __builtin_amdgcn_global_load_lds(
        (const __attribute__((address_space(1))) unsigned int*)g,
        (__attribute__((address_space(3))) unsigned int*)l, 16, 0, 0);
}

// ---------------- zero meta ----------------
__global__ void k_zero(int* meta){
    if (threadIdx.x < 64) meta[threadIdx.x] = 0;   // nflag@48
}

// ---------------- weight convert + transpose to bf16 [N][K] ----------------
__global__ __launch_bounds__(256) void k_convert(
    const float* __restrict__ We, const float* __restrict__ W1,
    const float* __restrict__ W2, const float* __restrict__ Wt,
    const float* __restrict__ Wc,
    bf16_t* __restrict__ WeHi, bf16_t* __restrict__ WeLo,
    bf16_t* __restrict__ W1T,
    bf16_t* __restrict__ W2T, bf16_t* __restrict__ WtT, bf16_t* __restrict__ WcT)
{
    int idx = blockIdx.x*256 + threadIdx.x;
    if (idx < 196608){ int n=idx/768, k=idx%768; float f = We[k*256+n];
        bf16_t h = (bf16_t)f; WeHi[idx] = h; WeLo[idx] = (bf16_t)(f - (float)h); return; }
    idx -= 196608;
    if (idx < 524288){ int e=idx>>16, r=idx&65535, n=r>>8, k=r&255;
        W1T[(e<<16)+(n<<8)+k] = (bf16_t)W1[(e<<16)+(k<<8)+n]; return; }
    idx -= 524288;
    if (idx < 524288){ int e=idx>>16, r=idx&65535, n=r>>8, k=r&255;
        W2T[(e<<16)+(n<<8)+k] = (bf16_t)W2[(e<<16)+(k<<8)+n]; return; }
    idx -= 524288;
    if (idx < 262144){ int n=idx>>8, k=idx&255; WtT[idx] = (bf16_t)Wt[k*1024+n]; return; }
    idx -= 262144;
    if (idx < 65536){ int n=idx>>8, k=idx&255; WcT[idx] = (bf16_t)Wc[k*256+n]; return; }
}

// ---------------- embed (split-bf16, 3-pass): X = gelu(x@We+be); l2f/clf (+bf16 copies) ----------------
__global__ __launch_bounds__(256) void k_embed(
    const float* __restrict__ x, const bf16_t* __restrict__ WeHi,
    const bf16_t* __restrict__ WeLo,
    const float* __restrict__ be, const float* __restrict__ l2e,
    const float* __restrict__ cle,
    float* __restrict__ l2f, float* __restrict__ clf,
    bf16_t* __restrict__ l2h, bf16_t* __restrict__ clh)
{
    __shared__ bf16_t Ah[128][40];
    __shared__ bf16_t Al[128][40];
    __shared__ bf16_t Bh[64][40];
    __shared__ bf16_t Bl[64][40];
    int row0 = blockIdx.x*128, col0 = blockIdx.y*64;
    int t = threadIdx.x, wave = t>>6, lane = t&63;
    int wm = wave>>1, wn = wave&1;
    f32x4 acc[4][2] = {};
    for (int k0 = 0; k0 < TD; k0 += 32){
        __syncthreads();
        #pragma unroll
        for (int u=0; u<4; ++u){
            int fi = u*256 + t, r = fi>>3, q = fi&7;
            float4 v = *(const float4*)(x + (size_t)(row0+r)*TD + k0 + q*4);
            bf16x4 h = cvt4(v);
            float4 rl;
            rl.x = v.x-(float)h[0]; rl.y = v.y-(float)h[1];
            rl.z = v.z-(float)h[2]; rl.w = v.w-(float)h[3];
            *(bf16x4*)(&Ah[r][q*4]) = h;
            *(bf16x4*)(&Al[r][q*4]) = cvt4(rl);
        }
        {
            int r = t>>2, q = t&3;
            *(bf16x8*)(&Bh[r][q*8]) = *(const bf16x8*)(WeHi + (size_t)(col0+r)*TD + k0 + q*8);
            *(bf16x8*)(&Bl[r][q*8]) = *(const bf16x8*)(WeLo + (size_t)(col0+r)*TD + k0 + q*8);
        }
        __syncthreads();
        int kq = lane>>4, lr = lane&15;
        bf16x8 ah[4], al[4], bh[2], bl[2];
        #pragma unroll
        for (int m=0;m<4;++m){
            ah[m] = *(const bf16x8*)(&Ah[wm*64 + m*16 + lr][kq*8]);
            al[m] = *(const bf16x8*)(&Al[wm*64 + m*16 + lr][kq*8]);
        }
        #pragma unroll
        for (int n=0;n<2;++n){
            bh[n] = *(const bf16x8*)(&Bh[wn*32 + n*16 + lr][kq*8]);
            bl[n] = *(const bf16x8*)(&Bl[wn*32 + n*16 + lr][kq*8]);
        }
        #pragma unroll
        for (int m=0;m<4;++m)
            #pragma unroll
            for (int n=0;n<2;++n){
                acc[m][n] = mfma16(ah[m], bh[n], acc[m][n]);
                acc[m][n] = mfma16(ah[m], bl[n], acc[m][n]);
                acc[m][n] = mfma16(al[m], bh[n], acc[m][n]);
            }
    }
    int kq = lane>>4, lr = lane&15;
    #pragma unroll
    for (int n=0;n<2;++n){
        int col = col0 + wn*32 + n*16 + lr;
        float bv = be[col], lv = l2e[col], cv = cle[col];
        #pragma unroll
        for (int m=0;m<4;++m)
            #pragma unroll
            for (int r=0;r<4;++r){
                int row = row0 + wm*64 + m*16 + kq*4 + r;
                float v = gelu_f(acc[m][n][r] + bv);
                float vl = v + lv, vc = v + cv;
                l2f[(size_t)row*HD + col] = vl;
                clf[(size_t)row*HD + col] = vc;
                l2h[(size_t)row*HD + col] = (bf16_t)vl;
                clh[(size_t)row*HD + col] = (bf16_t)vc;
            }
    }
}

// ---------------- gate: softmax + top2 + near-tie flags ----------------
__global__ __launch_bounds__(256) void k_gate(
    const float* __restrict__ l2f, const float* __restrict__ clf,
    const float* __restrict__ gW, const float* __restrict__ gb,
    float* __restrict__ topv, int* __restrict__ topi,
    int* __restrict__ flaglist, int* __restrict__ nflag)
{
    __shared__ float gw[2048];
    int t = threadIdx.x;
    for (int i=t; i<2048; i+=256) gw[i] = gW[i];
    __syncthreads();
    int wave = t>>6, lane = t&63;
    int idx = blockIdx.x*4 + wave;
    int br = idx>>14, tok = idx&16383;
    const float* in = br ? clf : l2f;
    float4 v = *(const float4*)(in + (size_t)tok*HD + lane*4);
    float xv[4] = {v.x, v.y, v.z, v.w};
    float p[8];
    #pragma unroll
    for (int e=0;e<8;++e) p[e] = 0.f;
    #pragma unroll
    for (int j=0;j<4;++j){
        const float* g = &gw[(lane*4+j)*8];
        #pragma unroll
        for (int e=0;e<8;++e) p[e] += xv[j]*g[e];
    }
    #pragma unroll
    for (int e=0;e<8;++e){
        float s = p[e];
        #pragma unroll
        for (int o=32;o>0;o>>=1) s += __shfl_xor(s, o);
        p[e] = s + gb[e];
    }
    float mx = p[0];
    #pragma unroll
    for (int e=1;e<8;++e) mx = fmaxf(mx, p[e]);
    float den = 0.f;
    #pragma unroll
    for (int e=0;e<8;++e) den += expf(p[e]-mx);
    int i1 = 0; float m1 = p[0];
    #pragma unroll
    for (int e=1;e<8;++e) if (p[e] > m1){ m1 = p[e]; i1 = e; }
    int i2 = (i1==0)?1:0; float m2 = p[i2];
    #pragma unroll
    for (int e=0;e<8;++e) if (e != i1 && p[e] > m2){ m2 = p[e]; i2 = e; }
    if (lane == 0){
        topv[idx*2]   = expf(m1-mx)/den;
        topv[idx*2+1] = expf(m2-mx)/den;
        topi[idx*2]   = i1;
        topi[idx*2+1] = i2;
        float m3 = -1e30f;
        #pragma unroll
        for (int e=0;e<8;++e) if (e != i1 && e != i2) m3 = fmaxf(m3, p[e]);
        if (m2 - m3 < 1e-3f){
            int slot = atomicAdd(nflag, 1);
            if (slot < FLAG_CAP) flaglist[slot] = idx;
        }
    }
}

// ---------------- refine: exact f64 gating for near-tie tokens ----------------
__global__ __launch_bounds__(256) void k_refine(
    const float* __restrict__ x, const float* __restrict__ We,
    const float* __restrict__ be,
    const float* __restrict__ l2e, const float* __restrict__ cle,
    const float* __restrict__ gW, const float* __restrict__ gb,
    const int* __restrict__ flaglist, const int* __restrict__ nflag,
    float* __restrict__ topv, int* __restrict__ topi)
{
    __shared__ float xs[768];
    __shared__ double red[256][8];
    int t = threadIdx.x;
    int nf = *nflag; if (nf > FLAG_CAP) nf = FLAG_CAP;
    for (int f = blockIdx.x; f < nf; f += gridDim.x){
        int idx = flaglist[f];
        int br = idx>>14, tok = idx&16383;
        __syncthreads();
        for (int i=t; i<768; i+=256) xs[i] = x[(size_t)tok*768 + i];
        __syncthreads();
        double u = 0.0;
        for (int j=0;j<768;++j) u += (double)xs[j] * (double)We[(size_t)j*256 + t];
        u += (double)be[t];
        double act = 0.5*u*(1.0 + erf(u*0.70710678118654752440));
        double li = act + (double)(br ? cle[t] : l2e[t]);
        #pragma unroll
        for (int e=0;e<8;++e) red[t][e] = li * (double)gW[t*8+e];
        __syncthreads();
        for (int s=128; s>0; s>>=1){
            if (t < s){
                #pragma unroll
                for (int e=0;e<8;++e) red[t][e] += red[t+s][e];
            }
            __syncthreads();
        }
        if (t == 0){
            double p[8];
            #pragma unroll
            for (int e=0;e<8;++e) p[e] = red[0][e] + (double)gb[e];
            int i1 = 0; double m1 = p[0];
            #pragma unroll
            for (int e=1;e<8;++e) if (p[e] > m1){ m1 = p[e]; i1 = e; }
            int i2 = (i1==0)?1:0; double m2 = p[i2];
            #pragma unroll
            for (int e=0;e<8;++e) if (e != i1 && p[e] > m2){ m2 = p[e]; i2 = e; }
            double mx = m1, den = 0.0;
            #pragma unroll
            for (int e=0;e<8;++e) den += exp(p[e]-mx);
            topv[idx*2]   = (float)(exp(m1-mx)/den);
            topv[idx*2+1] = (float)(exp(m2-mx)/den);
            topi[idx*2]   = i1;
            topi[idx*2+1] = i2;
        }
    }
}

// ---------------- per-block histogram (LDS atomics only) ----------------
__global__ __launch_bounds__(256) void k_hist(
    const int* __restrict__ topi, int* __restrict__ blockhist)
{
    __shared__ int h[16];
    int t = threadIdx.x;
    if (t < 16) h[t] = 0;
    __syncthreads();
    int idx = blockIdx.x*256 + t;
    int br = idx>>14;
    atomicAdd(&h[br*8 + topi[idx*2]], 1);
    atomicAdd(&h[br*8 + topi[idx*2+1]], 1);
    __syncthreads();
    if (t < 16) blockhist[blockIdx.x*16 + t] = h[t];
}

// ---------------- scan: per-block bases + expert offsets + 128-row tile table ----------------
__global__ void k_scan(const int* __restrict__ blockhist, int* __restrict__ base,
                       int4* __restrict__ table)
{
    __shared__ int tot[16], off[16], tpre[2][9];
    int t = threadIdx.x;
    if (t < 16){
        int s = 0;
        for (int b=0;b<128;++b){ base[b*16+t] = s; s += blockhist[b*16+t]; }
        tot[t] = s;
    }
    __syncthreads();
    if (t == 0){
        for (int br=0;br<2;++br){
            int s=0, tp=0; tpre[br][0]=0;
            for (int e=0;e<8;++e){
                off[br*8+e]=s; s += tot[br*8+e];
                tp += (tot[br*8+e]+127)>>7; tpre[br][e+1]=tp;
            }
        }
    }
    __syncthreads();
    for (int i=t; i<2048; i+=256) base[i] += off[i&15];
    for (int i=t; i<2*MOE_TPB; i+=256){
        int b = i/MOE_TPB, ti = i%MOE_TPB;
        int4 ent = make_int4(-1,0,0,0);
        if (ti < tpre[b][8]){
            int e = 0;
            while (ti >= tpre[b][e+1]) ++e;
            int k = ti - tpre[b][e];
            int s = off[b*8+e] + k*128;
            int en = off[b*8+e] + tot[b*8+e];
            ent = make_int4(e, s, (s+128 < en) ? (s+128) : en, b);
        }
        table[i] = ent;
    }
}

// ---------------- scatter: LDS-local ranks + per-block base ----------------
__global__ __launch_bounds__(256) void k_scatter(
    const int* __restrict__ topi, const int* __restrict__ base,
    int* __restrict__ rows, int* __restrict__ posof)
{
    __shared__ int h[16];
    int t = threadIdx.x;
    if (t < 16) h[t] = 0;
    __syncthreads();
    int idx = blockIdx.x*256 + t;
    int br = idx>>14, tok = idx&16383;
    int e0 = topi[idx*2], e1 = topi[idx*2+1];
    int r0 = atomicAdd(&h[br*8+e0], 1);
    int r1 = atomicAdd(&h[br*8+e1], 1);
    int p0 = base[blockIdx.x*16 + br*8 + e0] + r0;
    int p1 = base[blockIdx.x*16 + br*8 + e1] + r1;
    rows[br*NPAIR + p0] = tok;
    rows[br*NPAIR + p1] = tok;
    posof[idx*2]   = p0;
    posof[idx*2+1] = p1;
}

// ---------------- grouped MoE: big reg budget, W2 preloaded to regs ----------------
__global__ __launch_bounds__(512, 2) void k_moe(
    const int4* __restrict__ table, const int* __restrict__ rows,
    const bf16_t* __restrict__ l2h, const bf16_t* __restrict__ clh,
    const bf16_t* __restrict__ W1T, const bf16_t* __restrict__ W2T,
    const float* __restrict__ b1, const float* __restrict__ b2,
    bf16_t* __restrict__ eo)
{
    int4 te = table[blockIdx.x];
    int e = te.x, start = te.y, end = te.z, br = te.w;
    if (e < 0) return;
    const bf16_t* inb = br ? clh : l2h;

    __shared__ bf16_t Hs[128*256];   // 64 KB: A-tile, then reused as h-tile (16B-chunk XOR row&7 swizzle)
    char* hb = (char*)Hs;

    int t = threadIdx.x, w = t>>6, lane = t&63;
    int wm = w>>2, wn = w&3;
    int kq = lane>>4, lr = lane&15;

    // ---- stage gathered A rows: wave w stages rows w*16..w*16+15, 2 rows (1KB) per call ----
    {
        int half = lane >> 5;            // row within the pair
        int ch   = lane & 31;            // 16B chunk within row
        #pragma unroll
        for (int u=0; u<8; ++u){
            int row = w*16 + u*2 + half;
            int pos = start + row;
            int tok = rows[br*NPAIR + ((pos < end) ? pos : start)];
            const bf16_t* src = inb + (size_t)tok*HD + (size_t)((ch ^ (row&7))*8);
            gload_lds16(src, hb + (w*16 + u*2)*512);
        }
    }
    __syncthreads();   // drains vmcnt (global_load_lds) before cross-wave LDS reads

    // ---- GEMM1: h = gelu(A @ W1 + b1); A from LDS, B global (deep-pipelined, 512-reg budget) ----
    const bf16_t* b1p = W1T + ((size_t)e<<16) + (size_t)(wn*64 + lr)*HD + kq*8;
    f32x4 acc[4][4] = {};
    #pragma unroll
    for (int k0=0;k0<8;++k0){
        bf16x8 af[4], bfr[4];
        #pragma unroll
        for (int m=0;m<4;++m){
            int row = wm*64 + m*16 + lr;
            af[m] = *(const bf16x8*)(hb + row*512 + (((k0*4 + kq) ^ (row&7))<<4));
        }
        #pragma unroll
        for (int n=0;n<4;++n) bfr[n] = *(const bf16x8*)(b1p + (size_t)(n*16)*HD + k0*32);
        #pragma unroll
        for (int m=0;m<4;++m)
            #pragma unroll
            for (int n=0;n<4;++n) acc[m][n] = mfma16(af[m], bfr[n], acc[m][n]);
    }

    // ---- preload ALL W2 fragments into registers (independent of h; hides under epilogue+barrier) ----
    const bf16_t* b2p = W2T + ((size_t)e<<16) + (size_t)(wn*64 + lr)*HD + kq*8;
    bf16x8 w2f[8][4];
    #pragma unroll
    for (int k0=0;k0<8;++k0)
        #pragma unroll
        for (int n=0;n<4;++n)
            w2f[k0][n] = *(const bf16x8*)(b2p + (size_t)(n*16)*HD + k0*32);

    __syncthreads();   // all A reads complete before overwrite with h
    #pragma unroll
    for (int n=0;n<4;++n){
        int col = wn*64 + n*16 + lr;
        float bv = b1[e*256 + col];
        #pragma unroll
        for (int m=0;m<4;++m)
            #pragma unroll
            for (int r=0;r<4;++r){
                int row = wm*64 + m*16 + kq*4 + r;
                int byte = row*512 + ((((col>>3) ^ (row&7))<<4)) + (col&7)*2;
                *(bf16_t*)(hb + byte) = (bf16_t)gelu_f(acc[m][n][r] + bv);
            }
    }
    __syncthreads();
    // ---- GEMM2: eo = h @ W2 + b2; h from LDS, W2 from registers — zero global loads ----
    #pragma unroll
    for (int m=0;m<4;++m)
        #pragma unroll
        for (int n=0;n<4;++n)
            #pragma unroll
            for (int r=0;r<4;++r) acc[m][n][r] = 0.f;
    #pragma unroll
    for (int k0=0;k0<8;++k0){
        bf16x8 af[4];
        #pragma unroll
        for (int m=0;m<4;++m){
            int row = wm*64 + m*16 + lr;
            af[m] = *(const bf16x8*)(hb + row*512 + (((k0*4 + kq) ^ (row&7))<<4));
        }
        #pragma unroll
        for (int m=0;m<4;++m)
            #pragma unroll
            for (int n=0;n<4;++n) acc[m][n] = mfma16(af[m], w2f[k0][n], acc[m][n]);
    }
    #pragma unroll
    for (int n=0;n<4;++n){
        int col = wn*64 + n*16 + lr;
        float bv = b2[e*256 + col];
        #pragma unroll
        for (int m=0;m<4;++m)
            #pragma unroll
            for (int r=0;r<4;++r){
                int pos = start + wm*64 + m*16 + kq*4 + r;
                if (pos < end)
                    eo[((size_t)br*NPAIR + pos)*HD + col] = (bf16_t)(acc[m][n][r] + bv);
            }
    }
}

// ---------------- combine + LN + gelu + residual -> y (bf16) ----------------
__global__ __launch_bounds__(256) void k_combine(
    const bf16_t* __restrict__ eo, const float* __restrict__ topv,
    const int* __restrict__ posof,
    const float* __restrict__ l2f, const float* __restrict__ clf,
    const float* __restrict__ l2g, const float* __restrict__ l2b,
    const float* __restrict__ clg, const float* __restrict__ clb,
    bf16_t* __restrict__ yl2, bf16_t* __restrict__ ycl)
{
    int t = threadIdx.x, wave = t>>6, lane = t&63;
    int idx = blockIdx.x*4 + wave;
    int br = idx>>14, tok = idx&16383;
    const float* in = br ? clf : l2f;
    const float* g  = br ? clg : l2g;
    const float* bb = br ? clb : l2b;
    bf16_t* y = br ? ycl : yl2;
    int p0 = posof[idx*2], p1 = posof[idx*2+1];
    float w0 = topv[idx*2], w1 = topv[idx*2+1];
    bf16x4 e0 = *(const bf16x4*)(eo + ((size_t)br*NPAIR + p0)*HD + lane*4);
    bf16x4 e1 = *(const bf16x4*)(eo + ((size_t)br*NPAIR + p1)*HD + lane*4);
    float v[4], s = 0.f, s2 = 0.f;
    #pragma unroll
    for (int j=0;j<4;++j){
        v[j] = w0*(float)e0[j] + w1*(float)e1[j];
        s += v[j]; s2 += v[j]*v[j];
    }
    #pragma unroll
    for (int o=32;o>0;o>>=1){ s += __shfl_xor(s, o); s2 += __shfl_xor(s2, o); }
    float mean = s * (1.f/256.f);
    float var  = s2 * (1.f/256.f) - mean*mean;
    float inv  = rsqrtf(var + 1e-5f);
    float4 iv = *(const float4*)(in + (size_t)tok*HD + lane*4);
    float ivv[4] = {iv.x, iv.y, iv.z, iv.w};
    bf16x4 ov;
    #pragma unroll
    for (int j=0;j<4;++j){
        int c = lane*4 + j;
        float ln = (v[j]-mean)*inv*g[c] + bb[c];
        ov[j] = (bf16_t)(gelu_f(ln) + ivv[j]);
    }
    *(bf16x4*)(y + (size_t)tok*HD + lane*4) = ov;
}

// ---------------- head GEMM: out = y @ W + bias (fp32 out) ----------------
__global__ __launch_bounds__(256) void k_head(
    const bf16_t* __restrict__ A, const bf16_t* __restrict__ BT,
    const float* __restrict__ bias, float* __restrict__ out, int Nout)
{
    __shared__ bf16_t As[128][40];
    __shared__ bf16_t Bs[64][40];
    int row0 = blockIdx.x*128, col0 = blockIdx.y*64;
    int t = threadIdx.x, wave = t>>6, lane = t&63;
    int wm = wave>>1, wn = wave&1;
    f32x4 acc[4][2] = {};
    for (int k0=0; k0<HD; k0+=32){
        __syncthreads();
        #pragma unroll
        for (int u=0;u<2;++u){
            int fi = u*256 + t, r = fi>>2, q = fi&3;
            *(bf16x8*)(&As[r][q*8]) = *(const bf16x8*)(A + (size_t)(row0+r)*HD + k0 + q*8);
        }
        {
            int r = t>>2, q = t&3;
            *(bf16x8*)(&Bs[r][q*8]) = *(const bf16x8*)(BT + (size_t)(col0+r)*HD + k0 + q*8);
        }
        __syncthreads();
        int kq = lane>>4, lr = lane&15;
        bf16x8 af[4], bfr[2];
        #pragma unroll
        for (int m=0;m<4;++m) af[m] = *(const bf16x8*)(&As[wm*64 + m*16 + lr][kq*8]);
        #pragma unroll
        for (int n=0;n<2;++n) bfr[n] = *(const bf16x8*)(&Bs[wn*32 + n*16 + lr][kq*8]);
        #pragma unroll
        for (int m=0;m<4;++m)
            #pragma unroll
            for (int n=0;n<2;++n) acc[m][n] = mfma16(af[m], bfr[n], acc[m][n]);
    }
    int kq = lane>>4, lr = lane&15;
    #pragma unroll
    for (int n=0;n<2;++n){
        int col = col0 + wn*32 + n*16 + lr;
        float bv = bias[col];
        #pragma unroll
        for (int m=0;m<4;++m)
            #pragma unroll
            for (int r=0;r<4;++r){
                int row = row0 + wm*64 + m*16 + kq*4 + r;
                out[(size_t)row*Nout + col] = acc[m][n][r] + bv;
            }
    }
}

extern "C" void kernel_launch(void* const* d_in, const int* in_sizes, int n_in,
                              void* d_out, int out_size, void* d_ws, size_t ws_size,
                              hipStream_t stream)
{
    const float* x   = (const float*)d_in[0];
    const float* We  = (const float*)d_in[1];
    const float* be  = (const float*)d_in[2];
    const float* l2e = (const float*)d_in[3];
    const float* cle = (const float*)d_in[4];
    const float* gW  = (const float*)d_in[5];
    const float* gb  = (const float*)d_in[6];
    const float* W1  = (const float*)d_in[7];
    const float* b1  = (const float*)d_in[8];
    const float* W2  = (const float*)d_in[9];
    const float* b2  = (const float*)d_in[10];
    const float* l2g = (const float*)d_in[11];
    const float* l2b = (const float*)d_in[12];
    const float* clg = (const float*)d_in[13];
    const float* clb = (const float*)d_in[14];
    const float* Wt  = (const float*)d_in[15];
    const float* bt  = (const float*)d_in[16];
    const float* Wcl = (const float*)d_in[17];
    const float* bcl = (const float*)d_in[18];
    float* out = (float*)d_out;
    char* ws = (char*)d_ws;

    // workspace layout (bytes) — NEED 88523520
    const size_t O_META  = 0;
    const size_t O_TABLE = 256;
    const size_t O_BH    = 8704;
    const size_t O_TOPV  = 17152;
    const size_t O_TOPI  = 279296;
    const size_t O_POSOF = 541440;
    const size_t O_ROWS  = 803584;
    const size_t O_WEHI  = 1065728;
    const size_t O_W1T   = 1458944;
    const size_t O_W2T   = 2507520;
    const size_t O_WTT   = 3556096;
    const size_t O_WCLT  = 4080384;
    const size_t O_L2F   = 4211456;
    const size_t O_CLF   = 20988672;
    const size_t O_EO    = 37765888;
    const size_t O_L2H   = 71320320;   // bf16 acts; aliased by yl2 (written after moe)
    const size_t O_CLH   = 79708928;   // bf16 acts; aliased by ycl
    const size_t O_WELO  = 88097536;
    const size_t O_FLAG  = 88490752;
    const size_t O_BASE  = 88507136;
    const size_t NEED    = 88523520;
    if (ws_size < NEED) return;

    int*    meta    = (int*)(ws + O_META);
    int*    nflag   = meta + 48;
    int4*   table   = (int4*)(ws + O_TABLE);
    int*    blockhist = (int*)(ws + O_BH);
    float*  topv    = (float*)(ws + O_TOPV);
    int*    topi    = (int*)(ws + O_TOPI);
    int*    posof   = (int*)(ws + O_POSOF);
    int*    rows    = (int*)(ws + O_ROWS);
    bf16_t* WeHi    = (bf16_t*)(ws + O_WEHI);
    bf16_t* WeLo    = (bf16_t*)(ws + O_WELO);
    int*    flaglist= (int*)(ws + O_FLAG);
    int*    basep   = (int*)(ws + O_BASE);
    bf16_t* W1T     = (bf16_t*)(ws + O_W1T);
    bf16_t* W2T     = (bf16_t*)(ws + O_W2T);
    bf16_t* WtT     = (bf16_t*)(ws + O_WTT);
    bf16_t* WcT     = (bf16_t*)(ws + O_WCLT);
    float*  l2f     = (float*)(ws + O_L2F);
    float*  clf     = (float*)(ws + O_CLF);
    bf16_t* eo      = (bf16_t*)(ws + O_EO);
    bf16_t* l2h     = (bf16_t*)(ws + O_L2H);
    bf16_t* clh     = (bf16_t*)(ws + O_CLH);
    bf16_t* yl2     = (bf16_t*)(ws + O_L2H);   // alias: l2h dead after k_moe
    bf16_t* ycl     = (bf16_t*)(ws + O_CLH);   // alias: clh dead after k_moe

    k_zero<<<1, 64, 0, stream>>>(meta);
    k_convert<<<6144, 256, 0, stream>>>(We, W1, W2, Wt, Wcl, WeHi, WeLo, W1T, W2T, WtT, WcT);
    k_embed<<<dim3(128,4), 256, 0, stream>>>(x, WeHi, WeLo, be, l2e, cle, l2f, clf, l2h, clh);
    k_gate<<<8192, 256, 0, stream>>>(l2f, clf, gW, gb, topv, topi, flaglist, nflag);
    k_refine<<<256, 256, 0, stream>>>(x, We, be, l2e, cle, gW, gb, flaglist, nflag, topv, topi);
    k_hist<<<128, 256, 0, stream>>>(topi, blockhist);
    k_scan<<<1, 256, 0, stream>>>(blockhist, basep, table);
    k_scatter<<<128, 256, 0, stream>>>(topi, basep, rows, posof);
    k_moe<<<2*MOE_TPB, 512, 0, stream>>>(table, rows, l2h, clh, W1T, W2T, b1, b2, eo);
    k_combine<<<8192, 256, 0, stream>>>(eo, topv, posof, l2f, clf, l2g, l2b, clg, clb, yl2, ycl);
    k_head<<<dim3(128,16), 256, 0, stream>>>(yl2, WtT, bt, out, 1024);
    k_head<<<dim3(128,4), 256, 0, stream>>>(ycl, WcT, bcl, out + (size_t)16777216, 256);
}

// Round 7
// 289.441 us; speedup vs baseline: 1.0186x; 1.0186x over previous
//
#include <hip/hip_runtime.h>
#include <hip/hip_bf16.h>
#include <math.h>

typedef __bf16 bf16_t;
typedef __bf16 bf16x4 __attribute__((ext_vector_type(4)));
typedef __bf16 bf16x8 __attribute__((ext_vector_type(8)));
typedef float  f32x4  __attribute__((ext_vector_type(4)));

#define NTOK 16384   // B*S
#define HD   256     // hidden
#define TD   768
#define ID   1024
#define NPAIR 32768  // NTOK*2 per branch
#define MOE_TPB 264  // 128-row tiles per branch (256 + 8 boundary)
#define FLAG_CAP 4096

__device__ inline float gelu_f(float x){
    return 0.5f * x * (1.0f + erff(x * 0.70710678118654752f));
}
__device__ inline bf16x4 cvt4(float4 a){
    bf16x4 o; o[0]=(bf16_t)a.x; o[1]=(bf16_t)a.y; o[2]=(bf16_t)a.z; o[3]=(bf16_t)a.w; return o;
}
__device__ inline f32x4 mfma16(bf16x8 a, bf16x8 b, f32x4 c){
    return __builtin_amdgcn_mfma_f32_16x16x32_bf16(a, b, c, 0, 0, 0);
}
// async global->LDS, 16B per lane; lds dest = wave-uniform base + lane*16
__device__ inline void gload_lds16(const void* g, void* l){
    __builtin_amdgcn_global_load_lds(
        (const __attribute__((address_space(1))) unsigned int*)g,
        (__attribute__((address_space(3))) unsigned int*)l, 16, 0, 0);
}

// ---------------- zero meta ----------------
__global__ void k_zero(int* meta){
    if (threadIdx.x < 64) meta[threadIdx.x] = 0;   // nflag@48
}

// ---------------- weight convert + transpose to bf16 [N][K] ----------------
__global__ __launch_bounds__(256) void k_convert(
    const float* __restrict__ We, const float* __restrict__ W1,
    const float* __restrict__ W2, const float* __restrict__ Wt,
    const float* __restrict__ Wc,
    bf16_t* __restrict__ WeHi, bf16_t* __restrict__ WeLo,
    bf16_t* __restrict__ W1T,
    bf16_t* __restrict__ W2T, bf16_t* __restrict__ WtT, bf16_t* __restrict__ WcT)
{
    int idx = blockIdx.x*256 + threadIdx.x;
    if (idx < 196608){ int n=idx/768, k=idx%768; float f = We[k*256+n];
        bf16_t h = (bf16_t)f; WeHi[idx] = h; WeLo[idx] = (bf16_t)(f - (float)h); return; }
    idx -= 196608;
    if (idx < 524288){ int e=idx>>16, r=idx&65535, n=r>>8, k=r&255;
        W1T[(e<<16)+(n<<8)+k] = (bf16_t)W1[(e<<16)+(k<<8)+n]; return; }
    idx -= 524288;
    if (idx < 524288){ int e=idx>>16, r=idx&65535, n=r>>8, k=r&255;
        W2T[(e<<16)+(n<<8)+k] = (bf16_t)W2[(e<<16)+(k<<8)+n]; return; }
    idx -= 524288;
    if (idx < 262144){ int n=idx>>8, k=idx&255; WtT[idx] = (bf16_t)Wt[k*1024+n]; return; }
    idx -= 262144;
    if (idx < 65536){ int n=idx>>8, k=idx&255; WcT[idx] = (bf16_t)Wc[k*256+n]; return; }
}

// ---------------- embed (split-bf16, 3-pass): X = gelu(x@We+be); l2f/clf fp32 only ----------------
__global__ __launch_bounds__(256) void k_embed(
    const float* __restrict__ x, const bf16_t* __restrict__ WeHi,
    const bf16_t* __restrict__ WeLo,
    const float* __restrict__ be, const float* __restrict__ l2e,
    const float* __restrict__ cle,
    float* __restrict__ l2f, float* __restrict__ clf)
{
    __shared__ bf16_t Ah[128][40];
    __shared__ bf16_t Al[128][40];
    __shared__ bf16_t Bh[64][40];
    __shared__ bf16_t Bl[64][40];
    int row0 = blockIdx.x*128, col0 = blockIdx.y*64;
    int t = threadIdx.x, wave = t>>6, lane = t&63;
    int wm = wave>>1, wn = wave&1;
    f32x4 acc[4][2] = {};
    for (int k0 = 0; k0 < TD; k0 += 32){
        __syncthreads();
        #pragma unroll
        for (int u=0; u<4; ++u){
            int fi = u*256 + t, r = fi>>3, q = fi&7;
            float4 v = *(const float4*)(x + (size_t)(row0+r)*TD + k0 + q*4);
            bf16x4 h = cvt4(v);
            float4 rl;
            rl.x = v.x-(float)h[0]; rl.y = v.y-(float)h[1];
            rl.z = v.z-(float)h[2]; rl.w = v.w-(float)h[3];
            *(bf16x4*)(&Ah[r][q*4]) = h;
            *(bf16x4*)(&Al[r][q*4]) = cvt4(rl);
        }
        {
            int r = t>>2, q = t&3;
            *(bf16x8*)(&Bh[r][q*8]) = *(const bf16x8*)(WeHi + (size_t)(col0+r)*TD + k0 + q*8);
            *(bf16x8*)(&Bl[r][q*8]) = *(const bf16x8*)(WeLo + (size_t)(col0+r)*TD + k0 + q*8);
        }
        __syncthreads();
        int kq = lane>>4, lr = lane&15;
        bf16x8 ah[4], al[4], bh[2], bl[2];
        #pragma unroll
        for (int m=0;m<4;++m){
            ah[m] = *(const bf16x8*)(&Ah[wm*64 + m*16 + lr][kq*8]);
            al[m] = *(const bf16x8*)(&Al[wm*64 + m*16 + lr][kq*8]);
        }
        #pragma unroll
        for (int n=0;n<2;++n){
            bh[n] = *(const bf16x8*)(&Bh[wn*32 + n*16 + lr][kq*8]);
            bl[n] = *(const bf16x8*)(&Bl[wn*32 + n*16 + lr][kq*8]);
        }
        #pragma unroll
        for (int m=0;m<4;++m)
            #pragma unroll
            for (int n=0;n<2;++n){
                acc[m][n] = mfma16(ah[m], bh[n], acc[m][n]);
                acc[m][n] = mfma16(ah[m], bl[n], acc[m][n]);
                acc[m][n] = mfma16(al[m], bh[n], acc[m][n]);
            }
    }
    int kq = lane>>4, lr = lane&15;
    #pragma unroll
    for (int n=0;n<2;++n){
        int col = col0 + wn*32 + n*16 + lr;
        float bv = be[col], lv = l2e[col], cv = cle[col];
        #pragma unroll
        for (int m=0;m<4;++m)
            #pragma unroll
            for (int r=0;r<4;++r){
                int row = row0 + wm*64 + m*16 + kq*4 + r;
                float v = gelu_f(acc[m][n][r] + bv);
                l2f[(size_t)row*HD + col] = v + lv;
                clf[(size_t)row*HD + col] = v + cv;
            }
    }
}

// ---------------- gate: softmax + top2 + near-tie flags + bf16 activation emit ----------------
__global__ __launch_bounds__(256) void k_gate(
    const float* __restrict__ l2f, const float* __restrict__ clf,
    const float* __restrict__ gW, const float* __restrict__ gb,
    float* __restrict__ topv, int* __restrict__ topi,
    int* __restrict__ flaglist, int* __restrict__ nflag,
    bf16_t* __restrict__ l2h, bf16_t* __restrict__ clh)
{
    __shared__ float gw[2048];
    int t = threadIdx.x;
    for (int i=t; i<2048; i+=256) gw[i] = gW[i];
    __syncthreads();
    int wave = t>>6, lane = t&63;
    int idx = blockIdx.x*4 + wave;
    int br = idx>>14, tok = idx&16383;
    const float* in = br ? clf : l2f;
    float4 v = *(const float4*)(in + (size_t)tok*HD + lane*4);
    float xv[4] = {v.x, v.y, v.z, v.w};
    // coalesced bf16 activation copy (512B contiguous per wave)
    {
        bf16x4 hv; hv[0]=(bf16_t)v.x; hv[1]=(bf16_t)v.y; hv[2]=(bf16_t)v.z; hv[3]=(bf16_t)v.w;
        bf16_t* hout = br ? clh : l2h;
        *(bf16x4*)(hout + (size_t)tok*HD + lane*4) = hv;
    }
    float p[8];
    #pragma unroll
    for (int e=0;e<8;++e) p[e] = 0.f;
    #pragma unroll
    for (int j=0;j<4;++j){
        const float* g = &gw[(lane*4+j)*8];
        #pragma unroll
        for (int e=0;e<8;++e) p[e] += xv[j]*g[e];
    }
    #pragma unroll
    for (int e=0;e<8;++e){
        float s = p[e];
        #pragma unroll
        for (int o=32;o>0;o>>=1) s += __shfl_xor(s, o);
        p[e] = s + gb[e];
    }
    float mx = p[0];
    #pragma unroll
    for (int e=1;e<8;++e) mx = fmaxf(mx, p[e]);
    float den = 0.f;
    #pragma unroll
    for (int e=0;e<8;++e) den += expf(p[e]-mx);
    int i1 = 0; float m1 = p[0];
    #pragma unroll
    for (int e=1;e<8;++e) if (p[e] > m1){ m1 = p[e]; i1 = e; }
    int i2 = (i1==0)?1:0; float m2 = p[i2];
    #pragma unroll
    for (int e=0;e<8;++e) if (e != i1 && p[e] > m2){ m2 = p[e]; i2 = e; }
    if (lane == 0){
        topv[idx*2]   = expf(m1-mx)/den;
        topv[idx*2+1] = expf(m2-mx)/den;
        topi[idx*2]   = i1;
        topi[idx*2+1] = i2;
        float m3 = -1e30f;
        #pragma unroll
        for (int e=0;e<8;++e) if (e != i1 && e != i2) m3 = fmaxf(m3, p[e]);
        if (m2 - m3 < 1e-3f){
            int slot = atomicAdd(nflag, 1);
            if (slot < FLAG_CAP) flaglist[slot] = idx;
        }
    }
}

// ---------------- refine: exact f64 gating for near-tie tokens ----------------
__global__ __launch_bounds__(256) void k_refine(
    const float* __restrict__ x, const float* __restrict__ We,
    const float* __restrict__ be,
    const float* __restrict__ l2e, const float* __restrict__ cle,
    const float* __restrict__ gW, const float* __restrict__ gb,
    const int* __restrict__ flaglist, const int* __restrict__ nflag,
    float* __restrict__ topv, int* __restrict__ topi)
{
    __shared__ float xs[768];
    __shared__ double red[256][8];
    int t = threadIdx.x;
    int nf = *nflag; if (nf > FLAG_CAP) nf = FLAG_CAP;
    for (int f = blockIdx.x; f < nf; f += gridDim.x){
        int idx = flaglist[f];
        int br = idx>>14, tok = idx&16383;
        __syncthreads();
        for (int i=t; i<768; i+=256) xs[i] = x[(size_t)tok*768 + i];
        __syncthreads();
        double u = 0.0;
        for (int j=0;j<768;++j) u += (double)xs[j] * (double)We[(size_t)j*256 + t];
        u += (double)be[t];
        double act = 0.5*u*(1.0 + erf(u*0.70710678118654752440));
        double li = act + (double)(br ? cle[t] : l2e[t]);
        #pragma unroll
        for (int e=0;e<8;++e) red[t][e] = li * (double)gW[t*8+e];
        __syncthreads();
        for (int s=128; s>0; s>>=1){
            if (t < s){
                #pragma unroll
                for (int e=0;e<8;++e) red[t][e] += red[t+s][e];
            }
            __syncthreads();
        }
        if (t == 0){
            double p[8];
            #pragma unroll
            for (int e=0;e<8;++e) p[e] = red[0][e] + (double)gb[e];
            int i1 = 0; double m1 = p[0];
            #pragma unroll
            for (int e=1;e<8;++e) if (p[e] > m1){ m1 = p[e]; i1 = e; }
            int i2 = (i1==0)?1:0; double m2 = p[i2];
            #pragma unroll
            for (int e=0;e<8;++e) if (e != i1 && p[e] > m2){ m2 = p[e]; i2 = e; }
            double mx = m1, den = 0.0;
            #pragma unroll
            for (int e=0;e<8;++e) den += exp(p[e]-mx);
            topv[idx*2]   = (float)(exp(m1-mx)/den);
            topv[idx*2+1] = (float)(exp(m2-mx)/den);
            topi[idx*2]   = i1;
            topi[idx*2+1] = i2;
        }
    }
}

// ---------------- per-block histogram (LDS atomics only) ----------------
__global__ __launch_bounds__(256) void k_hist(
    const int* __restrict__ topi, int* __restrict__ blockhist)
{
    __shared__ int h[16];
    int t = threadIdx.x;
    if (t < 16) h[t] = 0;
    __syncthreads();
    int idx = blockIdx.x*256 + t;
    int br = idx>>14;
    atomicAdd(&h[br*8 + topi[idx*2]], 1);
    atomicAdd(&h[br*8 + topi[idx*2+1]], 1);
    __syncthreads();
    if (t < 16) blockhist[blockIdx.x*16 + t] = h[t];
}

// ---------------- scan: per-block bases + expert offsets + 128-row tile table ----------------
__global__ void k_scan(const int* __restrict__ blockhist, int* __restrict__ base,
                       int4* __restrict__ table)
{
    __shared__ int tot[16], off[16], tpre[2][9];
    int t = threadIdx.x;
    if (t < 16){
        int s = 0;
        for (int b=0;b<128;++b){ base[b*16+t] = s; s += blockhist[b*16+t]; }
        tot[t] = s;
    }
    __syncthreads();
    if (t == 0){
        for (int br=0;br<2;++br){
            int s=0, tp=0; tpre[br][0]=0;
            for (int e=0;e<8;++e){
                off[br*8+e]=s; s += tot[br*8+e];
                tp += (tot[br*8+e]+127)>>7; tpre[br][e+1]=tp;
            }
        }
    }
    __syncthreads();
    for (int i=t; i<2048; i+=256) base[i] += off[i&15];
    for (int i=t; i<2*MOE_TPB; i+=256){
        int b = i/MOE_TPB, ti = i%MOE_TPB;
        int4 ent = make_int4(-1,0,0,0);
        if (ti < tpre[b][8]){
            int e = 0;
            while (ti >= tpre[b][e+1]) ++e;
            int k = ti - tpre[b][e];
            int s = off[b*8+e] + k*128;
            int en = off[b*8+e] + tot[b*8+e];
            ent = make_int4(e, s, (s+128 < en) ? (s+128) : en, b);
        }
        table[i] = ent;
    }
}

// ---------------- scatter: LDS-local ranks + per-block base ----------------
__global__ __launch_bounds__(256) void k_scatter(
    const int* __restrict__ topi, const int* __restrict__ base,
    int* __restrict__ rows, int* __restrict__ posof)
{
    __shared__ int h[16];
    int t = threadIdx.x;
    if (t < 16) h[t] = 0;
    __syncthreads();
    int idx = blockIdx.x*256 + t;
    int br = idx>>14, tok = idx&16383;
    int e0 = topi[idx*2], e1 = topi[idx*2+1];
    int r0 = atomicAdd(&h[br*8+e0], 1);
    int r1 = atomicAdd(&h[br*8+e1], 1);
    int p0 = base[blockIdx.x*16 + br*8 + e0] + r0;
    int p1 = base[blockIdx.x*16 + br*8 + e1] + r1;
    rows[br*NPAIR + p0] = tok;
    rows[br*NPAIR + p1] = tok;
    posof[idx*2]   = p0;
    posof[idx*2+1] = p1;
}

// ---------------- grouped MoE: barrier-free k-loops + LDS-staged coalesced eo write ----------------
__global__ __launch_bounds__(512, 4) void k_moe(
    const int4* __restrict__ table, const int* __restrict__ rows,
    const bf16_t* __restrict__ l2h, const bf16_t* __restrict__ clh,
    const bf16_t* __restrict__ W1T, const bf16_t* __restrict__ W2T,
    const float* __restrict__ b1, const float* __restrict__ b2,
    bf16_t* __restrict__ eo)
{
    int4 te = table[blockIdx.x];
    int e = te.x, start = te.y, end = te.z, br = te.w;
    if (e < 0) return;
    const bf16_t* inb = br ? clh : l2h;

    __shared__ bf16_t Hs[128*256];   // 64 KB: A-tile -> h-tile -> out-tile (16B-chunk XOR row&7 swizzle)
    char* hb = (char*)Hs;

    int t = threadIdx.x, w = t>>6, lane = t&63;
    int wm = w>>2, wn = w&3;
    int kq = lane>>4, lr = lane&15;

    // ---- stage gathered A rows: wave w stages rows w*16..w*16+15, 2 rows (1KB) per call ----
    {
        int half = lane >> 5;            // row within the pair
        int ch   = lane & 31;            // 16B chunk within row
        #pragma unroll
        for (int u=0; u<8; ++u){
            int row = w*16 + u*2 + half;
            int pos = start + row;
            int tok = rows[br*NPAIR + ((pos < end) ? pos : start)];
            const bf16_t* src = inb + (size_t)tok*HD + (size_t)((ch ^ (row&7))*8);
            gload_lds16(src, hb + (w*16 + u*2)*512);
        }
    }
    __syncthreads();   // drains vmcnt (global_load_lds) before cross-wave LDS reads

    // ---- GEMM1: h = gelu(A @ W1 + b1); A from LDS, B direct-global (L2-hot), no barriers ----
    const bf16_t* b1p = W1T + ((size_t)e<<16) + (size_t)(wn*64 + lr)*HD + kq*8;
    f32x4 acc[4][4] = {};
    #pragma unroll
    for (int k0=0;k0<8;++k0){
        bf16x8 af[4], bfr[4];
        #pragma unroll
        for (int m=0;m<4;++m){
            int row = wm*64 + m*16 + lr;
            af[m] = *(const bf16x8*)(hb + row*512 + (((k0*4 + kq) ^ (row&7))<<4));
        }
        #pragma unroll
        for (int n=0;n<4;++n) bfr[n] = *(const bf16x8*)(b1p + (size_t)(n*16)*HD + k0*32);
        #pragma unroll
        for (int m=0;m<4;++m)
            #pragma unroll
            for (int n=0;n<4;++n) acc[m][n] = mfma16(af[m], bfr[n], acc[m][n]);
    }
    __syncthreads();   // all A reads complete before overwrite with h
    #pragma unroll
    for (int n=0;n<4;++n){
        int col = wn*64 + n*16 + lr;
        float bv = b1[e*256 + col];
        #pragma unroll
        for (int m=0;m<4;++m)
            #pragma unroll
            for (int r=0;r<4;++r){
                int row = wm*64 + m*16 + kq*4 + r;
                int byte = row*512 + ((((col>>3) ^ (row&7))<<4)) + (col&7)*2;
                *(bf16_t*)(hb + byte) = (bf16_t)gelu_f(acc[m][n][r] + bv);
            }
    }
    __syncthreads();
    // ---- GEMM2: eo = h @ W2 + b2; h from LDS (same swizzle), no barriers ----
    #pragma unroll
    for (int m=0;m<4;++m)
        #pragma unroll
        for (int n=0;n<4;++n)
            #pragma unroll
            for (int r=0;r<4;++r) acc[m][n][r] = 0.f;
    const bf16_t* b2p = W2T + ((size_t)e<<16) + (size_t)(wn*64 + lr)*HD + kq*8;
    #pragma unroll
    for (int k0=0;k0<8;++k0){
        bf16x8 af[4], bfr[4];
        #pragma unroll
        for (int m=0;m<4;++m){
            int row = wm*64 + m*16 + lr;
            af[m] = *(const bf16x8*)(hb + row*512 + (((k0*4 + kq) ^ (row&7))<<4));
        }
        #pragma unroll
        for (int n=0;n<4;++n) bfr[n] = *(const bf16x8*)(b2p + (size_t)(n*16)*HD + k0*32);
        #pragma unroll
        for (int m=0;m<4;++m)
            #pragma unroll
            for (int n=0;n<4;++n) acc[m][n] = mfma16(af[m], bfr[n], acc[m][n]);
    }
    __syncthreads();   // all h reads complete before overwrite with output
    // ---- epilogue: acc -> LDS (swizzled), then fully-coalesced bf16x8 stores ----
    #pragma unroll
    for (int n=0;n<4;++n){
        int col = wn*64 + n*16 + lr;
        float bv = b2[e*256 + col];
        #pragma unroll
        for (int m=0;m<4;++m)
            #pragma unroll
            for (int r=0;r<4;++r){
                int row = wm*64 + m*16 + kq*4 + r;
                int byte = row*512 + ((((col>>3) ^ (row&7))<<4)) + (col&7)*2;
                *(bf16_t*)(hb + byte) = (bf16_t)(acc[m][n][r] + bv);
            }
    }
    __syncthreads();
    #pragma unroll
    for (int i=0;i<8;++i){
        int c = i*512 + t;              // 16B chunk id, 0..4095
        int row = c>>5, cir = c&31;     // 32 chunks per 512B row
        bf16x8 v = *(const bf16x8*)(hb + row*512 + ((cir ^ (row&7))<<4));
        int pos = start + row;
        if (pos < end)
            *(bf16x8*)(eo + ((size_t)br*NPAIR + pos)*HD + cir*8) = v;
    }
}

// ---------------- combine + LN + gelu + residual -> y (bf16) ----------------
__global__ __launch_bounds__(256) void k_combine(
    const bf16_t* __restrict__ eo, const float* __restrict__ topv,
    const int* __restrict__ posof,
    const float* __restrict__ l2f, const float* __restrict__ clf,
    const float* __restrict__ l2g, const float* __restrict__ l2b,
    const float* __restrict__ clg, const float* __restrict__ clb,
    bf16_t* __restrict__ yl2, bf16_t* __restrict__ ycl)
{
    int t = threadIdx.x, wave = t>>6, lane = t&63;
    int idx = blockIdx.x*4 + wave;
    int br = idx>>14, tok = idx&16383;
    const float* in = br ? clf : l2f;
    const float* g  = br ? clg : l2g;
    const float* bb = br ? clb : l2b;
    bf16_t* y = br ? ycl : yl2;
    int p0 = posof[idx*2], p1 = posof[idx*2+1];
    float w0 = topv[idx*2], w1 = topv[idx*2+1];
    bf16x4 e0 = *(const bf16x4*)(eo + ((size_t)br*NPAIR + p0)*HD + lane*4);
    bf16x4 e1 = *(const bf16x4*)(eo + ((size_t)br*NPAIR + p1)*HD + lane*4);
    float v[4], s = 0.f, s2 = 0.f;
    #pragma unroll
    for (int j=0;j<4;++j){
        v[j] = w0*(float)e0[j] + w1*(float)e1[j];
        s += v[j]; s2 += v[j]*v[j];
    }
    #pragma unroll
    for (int o=32;o>0;o>>=1){ s += __shfl_xor(s, o); s2 += __shfl_xor(s2, o); }
    float mean = s * (1.f/256.f);
    float var  = s2 * (1.f/256.f) - mean*mean;
    float inv  = rsqrtf(var + 1e-5f);
    float4 iv = *(const float4*)(in + (size_t)tok*HD + lane*4);
    float ivv[4] = {iv.x, iv.y, iv.z, iv.w};
    bf16x4 ov;
    #pragma unroll
    for (int j=0;j<4;++j){
        int c = lane*4 + j;
        float ln = (v[j]-mean)*inv*g[c] + bb[c];
        ov[j] = (bf16_t)(gelu_f(ln) + ivv[j]);
    }
    *(bf16x4*)(y + (size_t)tok*HD + lane*4) = ov;
}

// ---------------- head GEMM: out = y @ W + bias (fp32 out) ----------------
__global__ __launch_bounds__(256) void k_head(
    const bf16_t* __restrict__ A, const bf16_t* __restrict__ BT,
    const float* __restrict__ bias, float* __restrict__ out, int Nout)
{
    __shared__ bf16_t As[128][40];
    __shared__ bf16_t Bs[64][40];
    int row0 = blockIdx.x*128, col0 = blockIdx.y*64;
    int t = threadIdx.x, wave = t>>6, lane = t&63;
    int wm = wave>>1, wn = wave&1;
    f32x4 acc[4][2] = {};
    for (int k0=0; k0<HD; k0+=32){
        __syncthreads();
        #pragma unroll
        for (int u=0;u<2;++u){
            int fi = u*256 + t, r = fi>>2, q = fi&3;
            *(bf16x8*)(&As[r][q*8]) = *(const bf16x8*)(A + (size_t)(row0+r)*HD + k0 + q*8);
        }
        {
            int r = t>>2, q = t&3;
            *(bf16x8*)(&Bs[r][q*8]) = *(const bf16x8*)(BT + (size_t)(col0+r)*HD + k0 + q*8);
        }
        __syncthreads();
        int kq = lane>>4, lr = lane&15;
        bf16x8 af[4], bfr[2];
        #pragma unroll
        for (int m=0;m<4;++m) af[m] = *(const bf16x8*)(&As[wm*64 + m*16 + lr][kq*8]);
        #pragma unroll
        for (int n=0;n<2;++n) bfr[n] = *(const bf16x8*)(&Bs[wn*32 + n*16 + lr][kq*8]);
        #pragma unroll
        for (int m=0;m<4;++m)
            #pragma unroll
            for (int n=0;n<2;++n) acc[m][n] = mfma16(af[m], bfr[n], acc[m][n]);
    }
    int kq = lane>>4, lr = lane&15;
    #pragma unroll
    for (int n=0;n<2;++n){
        int col = col0 + wn*32 + n*16 + lr;
        float bv = bias[col];
        #pragma unroll
        for (int m=0;m<4;++m)
            #pragma unroll
            for (int r=0;r<4;++r){
                int row = row0 + wm*64 + m*16 + kq*4 + r;
                out[(size_t)row*Nout + col] = acc[m][n][r] + bv;
            }
    }
}

extern "C" void kernel_launch(void* const* d_in, const int* in_sizes, int n_in,
                              void* d_out, int out_size, void* d_ws, size_t ws_size,
                              hipStream_t stream)
{
    const float* x   = (const float*)d_in[0];
    const float* We  = (const float*)d_in[1];
    const float* be  = (const float*)d_in[2];
    const float* l2e = (const float*)d_in[3];
    const float* cle = (const float*)d_in[4];
    const float* gW  = (const float*)d_in[5];
    const float* gb  = (const float*)d_in[6];
    const float* W1  = (const float*)d_in[7];
    const float* b1  = (const float*)d_in[8];
    const float* W2  = (const float*)d_in[9];
    const float* b2  = (const float*)d_in[10];
    const float* l2g = (const float*)d_in[11];
    const float* l2b = (const float*)d_in[12];
    const float* clg = (const float*)d_in[13];
    const float* clb = (const float*)d_in[14];
    const float* Wt  = (const float*)d_in[15];
    const float* bt  = (const float*)d_in[16];
    const float* Wcl = (const float*)d_in[17];
    const float* bcl = (const float*)d_in[18];
    float* out = (float*)d_out;
    char* ws = (char*)d_ws;

    // workspace layout (bytes) — NEED 88523520
    const size_t O_META  = 0;
    const size_t O_TABLE = 256;
    const size_t O_BH    = 8704;
    const size_t O_TOPV  = 17152;
    const size_t O_TOPI  = 279296;
    const size_t O_POSOF = 541440;
    const size_t O_ROWS  = 803584;
    const size_t O_WEHI  = 1065728;
    const size_t O_W1T   = 1458944;
    const size_t O_W2T   = 2507520;
    const size_t O_WTT   = 3556096;
    const size_t O_WCLT  = 4080384;
    const size_t O_L2F   = 4211456;
    const size_t O_CLF   = 20988672;
    const size_t O_EO    = 37765888;
    const size_t O_L2H   = 71320320;   // bf16 acts; aliased by yl2 (written after moe)
    const size_t O_CLH   = 79708928;   // bf16 acts; aliased by ycl
    const size_t O_WELO  = 88097536;
    const size_t O_FLAG  = 88490752;
    const size_t O_BASE  = 88507136;
    const size_t NEED    = 88523520;
    if (ws_size < NEED) return;

    int*    meta    = (int*)(ws + O_META);
    int*    nflag   = meta + 48;
    int4*   table   = (int4*)(ws + O_TABLE);
    int*    blockhist = (int*)(ws + O_BH);
    float*  topv    = (float*)(ws + O_TOPV);
    int*    topi    = (int*)(ws + O_TOPI);
    int*    posof   = (int*)(ws + O_POSOF);
    int*    rows    = (int*)(ws + O_ROWS);
    bf16_t* WeHi    = (bf16_t*)(ws + O_WEHI);
    bf16_t* WeLo    = (bf16_t*)(ws + O_WELO);
    int*    flaglist= (int*)(ws + O_FLAG);
    int*    basep   = (int*)(ws + O_BASE);
    bf16_t* W1T     = (bf16_t*)(ws + O_W1T);
    bf16_t* W2T     = (bf16_t*)(ws + O_W2T);
    bf16_t* WtT     = (bf16_t*)(ws + O_WTT);
    bf16_t* WcT     = (bf16_t*)(ws + O_WCLT);
    float*  l2f     = (float*)(ws + O_L2F);
    float*  clf     = (float*)(ws + O_CLF);
    bf16_t* eo      = (bf16_t*)(ws + O_EO);
    bf16_t* l2h     = (bf16_t*)(ws + O_L2H);
    bf16_t* clh     = (bf16_t*)(ws + O_CLH);
    bf16_t* yl2     = (bf16_t*)(ws + O_L2H);   // alias: l2h dead after k_moe
    bf16_t* ycl     = (bf16_t*)(ws + O_CLH);   // alias: clh dead after k_moe

    k_zero<<<1, 64, 0, stream>>>(meta);
    k_convert<<<6144, 256, 0, stream>>>(We, W1, W2, Wt, Wcl, WeHi, WeLo, W1T, W2T, WtT, WcT);
    k_embed<<<dim3(128,4), 256, 0, stream>>>(x, WeHi, WeLo, be, l2e, cle, l2f, clf);
    k_gate<<<8192, 256, 0, stream>>>(l2f, clf, gW, gb, topv, topi, flaglist, nflag, l2h, clh);
    k_refine<<<256, 256, 0, stream>>>(x, We, be, l2e, cle, gW, gb, flaglist, nflag, topv, topi);
    k_hist<<<128, 256, 0, stream>>>(topi, blockhist);
    k_scan<<<1, 256, 0, stream>>>(blockhist, basep, table);
    k_scatter<<<128, 256, 0, stream>>>(topi, basep, rows, posof);
    k_moe<<<2*MOE_TPB, 512, 0, stream>>>(table, rows, l2h, clh, W1T, W2T, b1, b2, eo);
    k_combine<<<8192, 256, 0, stream>>>(eo, topv, posof, l2f, clf, l2g, l2b, clg, clb, yl2, ycl);
    k_head<<<dim3(128,16), 256, 0, stream>>>(yl2, WtT, bt, out, 1024);
    k_head<<<dim3(128,4), 256, 0, stream>>>(ycl, WcT, bcl, out + (size_t)16777216, 256);
}

// Round 8
// 267.584 us; speedup vs baseline: 1.1018x; 1.0817x over previous
//
#include <hip/hip_runtime.h>
#include <hip/hip_bf16.h>
#include <math.h>

typedef __bf16 bf16_t;
typedef __bf16 bf16x4 __attribute__((ext_vector_type(4)));
typedef __bf16 bf16x8 __attribute__((ext_vector_type(8)));
typedef float  f32x4  __attribute__((ext_vector_type(4)));

#define NTOK 16384   // B*S
#define HD   256     // hidden
#define TD   768
#define ID   1024
#define NPAIR 32768  // NTOK*2 per branch
#define MOE_TPB 520  // 64-row tiles per branch (512 + 8 boundary)
#define FLAG_CAP 4096

// fast erf: Abramowitz-Stegun 7.1.26, |err| <= 1.5e-7, branchless
__device__ inline float fast_erf(float x){
    float ax = fabsf(x);
    float t = 1.0f / (1.0f + 0.3275911f*ax);
    float y = t*(0.254829592f + t*(-0.284496736f + t*(1.421413741f +
              t*(-1.453152027f + t*1.061405429f))));
    float e = 1.0f - y*__expf(-ax*ax);
    return copysignf(e, x);
}
__device__ inline float gelu_f(float x){
    return 0.5f * x * (1.0f + fast_erf(x * 0.70710678118654752f));
}
__device__ inline bf16x4 cvt4(float4 a){
    bf16x4 o; o[0]=(bf16_t)a.x; o[1]=(bf16_t)a.y; o[2]=(bf16_t)a.z; o[3]=(bf16_t)a.w; return o;
}
__device__ inline f32x4 mfma16(bf16x8 a, bf16x8 b, f32x4 c){
    return __builtin_amdgcn_mfma_f32_16x16x32_bf16(a, b, c, 0, 0, 0);
}

// ---------------- zero meta ----------------
__global__ void k_zero(int* meta){
    if (threadIdx.x < 64) meta[threadIdx.x] = 0;   // nflag@48
}

// ---------------- weight convert + transpose to bf16 [N][K] ----------------
__global__ __launch_bounds__(256) void k_convert(
    const float* __restrict__ We, const float* __restrict__ W1,
    const float* __restrict__ W2, const float* __restrict__ Wt,
    const float* __restrict__ Wc,
    bf16_t* __restrict__ WeHi, bf16_t* __restrict__ WeLo,
    bf16_t* __restrict__ W1T,
    bf16_t* __restrict__ W2T, bf16_t* __restrict__ WtT, bf16_t* __restrict__ WcT)
{
    int idx = blockIdx.x*256 + threadIdx.x;
    if (idx < 196608){ int n=idx/768, k=idx%768; float f = We[k*256+n];
        bf16_t h = (bf16_t)f; WeHi[idx] = h; WeLo[idx] = (bf16_t)(f - (float)h); return; }
    idx -= 196608;
    if (idx < 524288){ int e=idx>>16, r=idx&65535, n=r>>8, k=r&255;
        W1T[(e<<16)+(n<<8)+k] = (bf16_t)W1[(e<<16)+(k<<8)+n]; return; }
    idx -= 524288;
    if (idx < 524288){ int e=idx>>16, r=idx&65535, n=r>>8, k=r&255;
        W2T[(e<<16)+(n<<8)+k] = (bf16_t)W2[(e<<16)+(k<<8)+n]; return; }
    idx -= 524288;
    if (idx < 262144){ int n=idx>>8, k=idx&255; WtT[idx] = (bf16_t)Wt[k*1024+n]; return; }
    idx -= 262144;
    if (idx < 65536){ int n=idx>>8, k=idx&255; WcT[idx] = (bf16_t)Wc[k*256+n]; return; }
}

// ---------------- embed (split-bf16, 3-pass): X = gelu(x@We+be); l2f/clf fp32 only ----------------
__global__ __launch_bounds__(256) void k_embed(
    const float* __restrict__ x, const bf16_t* __restrict__ WeHi,
    const bf16_t* __restrict__ WeLo,
    const float* __restrict__ be, const float* __restrict__ l2e,
    const float* __restrict__ cle,
    float* __restrict__ l2f, float* __restrict__ clf)
{
    __shared__ bf16_t Ah[128][40];
    __shared__ bf16_t Al[128][40];
    __shared__ bf16_t Bh[64][40];
    __shared__ bf16_t Bl[64][40];
    int row0 = blockIdx.x*128, col0 = blockIdx.y*64;
    int t = threadIdx.x, wave = t>>6, lane = t&63;
    int wm = wave>>1, wn = wave&1;
    f32x4 acc[4][2] = {};
    for (int k0 = 0; k0 < TD; k0 += 32){
        __syncthreads();
        #pragma unroll
        for (int u=0; u<4; ++u){
            int fi = u*256 + t, r = fi>>3, q = fi&7;
            float4 v = *(const float4*)(x + (size_t)(row0+r)*TD + k0 + q*4);
            bf16x4 h = cvt4(v);
            float4 rl;
            rl.x = v.x-(float)h[0]; rl.y = v.y-(float)h[1];
            rl.z = v.z-(float)h[2]; rl.w = v.w-(float)h[3];
            *(bf16x4*)(&Ah[r][q*4]) = h;
            *(bf16x4*)(&Al[r][q*4]) = cvt4(rl);
        }
        {
            int r = t>>2, q = t&3;
            *(bf16x8*)(&Bh[r][q*8]) = *(const bf16x8*)(WeHi + (size_t)(col0+r)*TD + k0 + q*8);
            *(bf16x8*)(&Bl[r][q*8]) = *(const bf16x8*)(WeLo + (size_t)(col0+r)*TD + k0 + q*8);
        }
        __syncthreads();
        int kq = lane>>4, lr = lane&15;
        bf16x8 ah[4], al[4], bh[2], bl[2];
        #pragma unroll
        for (int m=0;m<4;++m){
            ah[m] = *(const bf16x8*)(&Ah[wm*64 + m*16 + lr][kq*8]);
            al[m] = *(const bf16x8*)(&Al[wm*64 + m*16 + lr][kq*8]);
        }
        #pragma unroll
        for (int n=0;n<2;++n){
            bh[n] = *(const bf16x8*)(&Bh[wn*32 + n*16 + lr][kq*8]);
            bl[n] = *(const bf16x8*)(&Bl[wn*32 + n*16 + lr][kq*8]);
        }
        #pragma unroll
        for (int m=0;m<4;++m)
            #pragma unroll
            for (int n=0;n<2;++n){
                acc[m][n] = mfma16(ah[m], bh[n], acc[m][n]);
                acc[m][n] = mfma16(ah[m], bl[n], acc[m][n]);
                acc[m][n] = mfma16(al[m], bh[n], acc[m][n]);
            }
    }
    int kq = lane>>4, lr = lane&15;
    #pragma unroll
    for (int n=0;n<2;++n){
        int col = col0 + wn*32 + n*16 + lr;
        float bv = be[col], lv = l2e[col], cv = cle[col];
        #pragma unroll
        for (int m=0;m<4;++m)
            #pragma unroll
            for (int r=0;r<4;++r){
                int row = row0 + wm*64 + m*16 + kq*4 + r;
                float v = gelu_f(acc[m][n][r] + bv);
                l2f[(size_t)row*HD + col] = v + lv;
                clf[(size_t)row*HD + col] = v + cv;
            }
    }
}

// ---------------- gate: softmax + top2 + near-tie flags + bf16 activation emit ----------------
__global__ __launch_bounds__(256) void k_gate(
    const float* __restrict__ l2f, const float* __restrict__ clf,
    const float* __restrict__ gW, const float* __restrict__ gb,
    float* __restrict__ topv, int* __restrict__ topi,
    int* __restrict__ flaglist, int* __restrict__ nflag,
    bf16_t* __restrict__ l2h, bf16_t* __restrict__ clh)
{
    __shared__ float gw[2048];
    int t = threadIdx.x;
    for (int i=t; i<2048; i+=256) gw[i] = gW[i];
    __syncthreads();
    int wave = t>>6, lane = t&63;
    int idx = blockIdx.x*4 + wave;
    int br = idx>>14, tok = idx&16383;
    const float* in = br ? clf : l2f;
    float4 v = *(const float4*)(in + (size_t)tok*HD + lane*4);
    float xv[4] = {v.x, v.y, v.z, v.w};
    {
        bf16x4 hv; hv[0]=(bf16_t)v.x; hv[1]=(bf16_t)v.y; hv[2]=(bf16_t)v.z; hv[3]=(bf16_t)v.w;
        bf16_t* hout = br ? clh : l2h;
        *(bf16x4*)(hout + (size_t)tok*HD + lane*4) = hv;
    }
    float p[8];
    #pragma unroll
    for (int e=0;e<8;++e) p[e] = 0.f;
    #pragma unroll
    for (int j=0;j<4;++j){
        const float* g = &gw[(lane*4+j)*8];
        #pragma unroll
        for (int e=0;e<8;++e) p[e] += xv[j]*g[e];
    }
    #pragma unroll
    for (int e=0;e<8;++e){
        float s = p[e];
        #pragma unroll
        for (int o=32;o>0;o>>=1) s += __shfl_xor(s, o);
        p[e] = s + gb[e];
    }
    float mx = p[0];
    #pragma unroll
    for (int e=1;e<8;++e) mx = fmaxf(mx, p[e]);
    float den = 0.f;
    #pragma unroll
    for (int e=0;e<8;++e) den += expf(p[e]-mx);
    int i1 = 0; float m1 = p[0];
    #pragma unroll
    for (int e=1;e<8;++e) if (p[e] > m1){ m1 = p[e]; i1 = e; }
    int i2 = (i1==0)?1:0; float m2 = p[i2];
    #pragma unroll
    for (int e=0;e<8;++e) if (e != i1 && p[e] > m2){ m2 = p[e]; i2 = e; }
    if (lane == 0){
        topv[idx*2]   = expf(m1-mx)/den;
        topv[idx*2+1] = expf(m2-mx)/den;
        topi[idx*2]   = i1;
        topi[idx*2+1] = i2;
        float m3 = -1e30f;
        #pragma unroll
        for (int e=0;e<8;++e) if (e != i1 && e != i2) m3 = fmaxf(m3, p[e]);
        if (m2 - m3 < 1e-3f){
            int slot = atomicAdd(nflag, 1);
            if (slot < FLAG_CAP) flaglist[slot] = idx;
        }
    }
}

// ---------------- refine: exact f64 gating for near-tie tokens ----------------
__global__ __launch_bounds__(256) void k_refine(
    const float* __restrict__ x, const float* __restrict__ We,
    const float* __restrict__ be,
    const float* __restrict__ l2e, const float* __restrict__ cle,
    const float* __restrict__ gW, const float* __restrict__ gb,
    const int* __restrict__ flaglist, const int* __restrict__ nflag,
    float* __restrict__ topv, int* __restrict__ topi)
{
    __shared__ float xs[768];
    __shared__ double red[256][8];
    int t = threadIdx.x;
    int nf = *nflag; if (nf > FLAG_CAP) nf = FLAG_CAP;
    for (int f = blockIdx.x; f < nf; f += gridDim.x){
        int idx = flaglist[f];
        int br = idx>>14, tok = idx&16383;
        __syncthreads();
        for (int i=t; i<768; i+=256) xs[i] = x[(size_t)tok*768 + i];
        __syncthreads();
        double u = 0.0;
        for (int j=0;j<768;++j) u += (double)xs[j] * (double)We[(size_t)j*256 + t];
        u += (double)be[t];
        double act = 0.5*u*(1.0 + erf(u*0.70710678118654752440));
        double li = act + (double)(br ? cle[t] : l2e[t]);
        #pragma unroll
        for (int e=0;e<8;++e) red[t][e] = li * (double)gW[t*8+e];
        __syncthreads();
        for (int s=128; s>0; s>>=1){
            if (t < s){
                #pragma unroll
                for (int e=0;e<8;++e) red[t][e] += red[t+s][e];
            }
            __syncthreads();
        }
        if (t == 0){
            double p[8];
            #pragma unroll
            for (int e=0;e<8;++e) p[e] = red[0][e] + (double)gb[e];
            int i1 = 0; double m1 = p[0];
            #pragma unroll
            for (int e=1;e<8;++e) if (p[e] > m1){ m1 = p[e]; i1 = e; }
            int i2 = (i1==0)?1:0; double m2 = p[i2];
            #pragma unroll
            for (int e=0;e<8;++e) if (e != i1 && p[e] > m2){ m2 = p[e]; i2 = e; }
            double mx = m1, den = 0.0;
            #pragma unroll
            for (int e=0;e<8;++e) den += exp(p[e]-mx);
            topv[idx*2]   = (float)(exp(m1-mx)/den);
            topv[idx*2+1] = (float)(exp(m2-mx)/den);
            topi[idx*2]   = i1;
            topi[idx*2+1] = i2;
        }
    }
}

// ---------------- per-block histogram (LDS atomics only) ----------------
__global__ __launch_bounds__(256) void k_hist(
    const int* __restrict__ topi, int* __restrict__ blockhist)
{
    __shared__ int h[16];
    int t = threadIdx.x;
    if (t < 16) h[t] = 0;
    __syncthreads();
    int idx = blockIdx.x*256 + t;
    int br = idx>>14;
    atomicAdd(&h[br*8 + topi[idx*2]], 1);
    atomicAdd(&h[br*8 + topi[idx*2+1]], 1);
    __syncthreads();
    if (t < 16) blockhist[blockIdx.x*16 + t] = h[t];
}

// ---------------- scan: per-block bases + expert offsets + 64-row tile table ----------------
__global__ void k_scan(const int* __restrict__ blockhist, int* __restrict__ base,
                       int4* __restrict__ table)
{
    __shared__ int tot[16], off[16], tpre[2][9];
    int t = threadIdx.x;
    if (t < 16){
        int s = 0;
        for (int b=0;b<128;++b){ base[b*16+t] = s; s += blockhist[b*16+t]; }
        tot[t] = s;
    }
    __syncthreads();
    if (t == 0){
        for (int br=0;br<2;++br){
            int s=0, tp=0; tpre[br][0]=0;
            for (int e=0;e<8;++e){
                off[br*8+e]=s; s += tot[br*8+e];
                tp += (tot[br*8+e]+63)>>6; tpre[br][e+1]=tp;
            }
        }
    }
    __syncthreads();
    for (int i=t; i<2048; i+=256) base[i] += off[i&15];
    for (int i=t; i<2*MOE_TPB; i+=256){
        int b = i/MOE_TPB, ti = i%MOE_TPB;
        int4 ent = make_int4(-1,0,0,0);
        if (ti < tpre[b][8]){
            int e = 0;
            while (ti >= tpre[b][e+1]) ++e;
            int k = ti - tpre[b][e];
            int s = off[b*8+e] + k*64;
            int en = off[b*8+e] + tot[b*8+e];
            ent = make_int4(e, s, (s+64 < en) ? (s+64) : en, b);
        }
        table[i] = ent;
    }
}

// ---------------- scatter: LDS-local ranks + per-block base ----------------
__global__ __launch_bounds__(256) void k_scatter(
    const int* __restrict__ topi, const int* __restrict__ base,
    int* __restrict__ rows, int* __restrict__ posof)
{
    __shared__ int h[16];
    int t = threadIdx.x;
    if (t < 16) h[t] = 0;
    __syncthreads();
    int idx = blockIdx.x*256 + t;
    int br = idx>>14, tok = idx&16383;
    int e0 = topi[idx*2], e1 = topi[idx*2+1];
    int r0 = atomicAdd(&h[br*8+e0], 1);
    int r1 = atomicAdd(&h[br*8+e1], 1);
    int p0 = base[blockIdx.x*16 + br*8 + e0] + r0;
    int p1 = base[blockIdx.x*16 + br*8 + e1] + r1;
    rows[br*NPAIR + p0] = tok;
    rows[br*NPAIR + p1] = tok;
    posof[idx*2]   = p0;
    posof[idx*2+1] = p1;
}

// ---------------- grouped MoE: BM=64, 32KB LDS (h handoff + coalesced store), barrier-free k-loops ----------------
__global__ __launch_bounds__(512, 4) void k_moe(
    const int4* __restrict__ table, const int* __restrict__ rows,
    const bf16_t* __restrict__ l2h, const bf16_t* __restrict__ clh,
    const bf16_t* __restrict__ W1T, const bf16_t* __restrict__ W2T,
    const float* __restrict__ b1, const float* __restrict__ b2,
    bf16_t* __restrict__ eo)
{
    int4 te = table[blockIdx.x];
    int e = te.x, start = te.y, end = te.z, br = te.w;
    if (e < 0) return;
    const bf16_t* inb = br ? clh : l2h;

    __shared__ bf16_t Hs[64*256];   // 32 KB: h-tile then out-tile (16B-chunk XOR row&7 swizzle)
    char* hb = (char*)Hs;

    int t = threadIdx.x, w = t>>6, lane = t&63;
    int wm = w>>2, wn = w&3;          // wave: 32 rows x 64 cols
    int kq = lane>>4, lr = lane&15;

    // A row offsets (gathered rows, k-invariant)
    int rowoff[2];
    #pragma unroll
    for (int m=0;m<2;++m){
        int pos = start + wm*32 + m*16 + lr;
        int tok = rows[br*NPAIR + ((pos < end) ? pos : start)];
        rowoff[m] = tok*HD + kq*8;
    }
    // ---- GEMM1: h = gelu(A @ W1 + b1); A,B direct-global, no barriers ----
    const bf16_t* b1p = W1T + ((size_t)e<<16) + (size_t)(wn*64 + lr)*HD + kq*8;
    f32x4 acc[2][4] = {};
    #pragma unroll
    for (int k0=0;k0<8;++k0){
        bf16x8 af[2], bfr[4];
        #pragma unroll
        for (int m=0;m<2;++m) af[m] = *(const bf16x8*)(inb + rowoff[m] + k0*32);
        #pragma unroll
        for (int n=0;n<4;++n) bfr[n] = *(const bf16x8*)(b1p + (size_t)(n*16)*HD + k0*32);
        #pragma unroll
        for (int m=0;m<2;++m)
            #pragma unroll
            for (int n=0;n<4;++n) acc[m][n] = mfma16(af[m], bfr[n], acc[m][n]);
    }
    // h -> LDS (swizzled)
    #pragma unroll
    for (int n=0;n<4;++n){
        int col = wn*64 + n*16 + lr;
        float bv = b1[e*256 + col];
        #pragma unroll
        for (int m=0;m<2;++m)
            #pragma unroll
            for (int r=0;r<4;++r){
                int row = wm*32 + m*16 + kq*4 + r;
                int byte = row*512 + ((((col>>3) ^ (row&7))<<4)) + (col&7)*2;
                *(bf16_t*)(hb + byte) = (bf16_t)gelu_f(acc[m][n][r] + bv);
            }
    }
    __syncthreads();
    // ---- GEMM2: eo = h @ W2 + b2; h from LDS, B direct-global, no barriers ----
    #pragma unroll
    for (int m=0;m<2;++m)
        #pragma unroll
        for (int n=0;n<4;++n)
            #pragma unroll
            for (int r=0;r<4;++r) acc[m][n][r] = 0.f;
    const bf16_t* b2p = W2T + ((size_t)e<<16) + (size_t)(wn*64 + lr)*HD + kq*8;
    #pragma unroll
    for (int k0=0;k0<8;++k0){
        bf16x8 af[2], bfr[4];
        #pragma unroll
        for (int m=0;m<2;++m){
            int row = wm*32 + m*16 + lr;
            af[m] = *(const bf16x8*)(hb + row*512 + (((k0*4 + kq) ^ (row&7))<<4));
        }
        #pragma unroll
        for (int n=0;n<4;++n) bfr[n] = *(const bf16x8*)(b2p + (size_t)(n*16)*HD + k0*32);
        #pragma unroll
        for (int m=0;m<2;++m)
            #pragma unroll
            for (int n=0;n<4;++n) acc[m][n] = mfma16(af[m], bfr[n], acc[m][n]);
    }
    __syncthreads();   // all h reads done before overwrite
    // out -> LDS (swizzled)
    #pragma unroll
    for (int n=0;n<4;++n){
        int col = wn*64 + n*16 + lr;
        float bv = b2[e*256 + col];
        #pragma unroll
        for (int m=0;m<2;++m)
            #pragma unroll
            for (int r=0;r<4;++r){
                int row = wm*32 + m*16 + kq*4 + r;
                int byte = row*512 + ((((col>>3) ^ (row&7))<<4)) + (col&7)*2;
                *(bf16_t*)(hb + byte) = (bf16_t)(acc[m][n][r] + bv);
            }
    }
    __syncthreads();
    // fully-coalesced bf16x8 stores (512B contiguous per row)
    #pragma unroll
    for (int i=0;i<4;++i){
        int c = i*512 + t;              // 16B chunk id, 0..2047
        int row = c>>5, cir = c&31;
        bf16x8 v = *(const bf16x8*)(hb + row*512 + ((cir ^ (row&7))<<4));
        int pos = start + row;
        if (pos < end)
            *(bf16x8*)(eo + ((size_t)br*NPAIR + pos)*HD + cir*8) = v;
    }
}

// ---------------- combine + LN + gelu + residual -> y (bf16) ----------------
__global__ __launch_bounds__(256) void k_combine(
    const bf16_t* __restrict__ eo, const float* __restrict__ topv,
    const int* __restrict__ posof,
    const float* __restrict__ l2f, const float* __restrict__ clf,
    const float* __restrict__ l2g, const float* __restrict__ l2b,
    const float* __restrict__ clg, const float* __restrict__ clb,
    bf16_t* __restrict__ yl2, bf16_t* __restrict__ ycl)
{
    int t = threadIdx.x, wave = t>>6, lane = t&63;
    int idx = blockIdx.x*4 + wave;
    int br = idx>>14, tok = idx&16383;
    const float* in = br ? clf : l2f;
    const float* g  = br ? clg : l2g;
    const float* bb = br ? clb : l2b;
    bf16_t* y = br ? ycl : yl2;
    int p0 = posof[idx*2], p1 = posof[idx*2+1];
    float w0 = topv[idx*2], w1 = topv[idx*2+1];
    bf16x4 e0 = *(const bf16x4*)(eo + ((size_t)br*NPAIR + p0)*HD + lane*4);
    bf16x4 e1 = *(const bf16x4*)(eo + ((size_t)br*NPAIR + p1)*HD + lane*4);
    float v[4], s = 0.f, s2 = 0.f;
    #pragma unroll
    for (int j=0;j<4;++j){
        v[j] = w0*(float)e0[j] + w1*(float)e1[j];
        s += v[j]; s2 += v[j]*v[j];
    }
    #pragma unroll
    for (int o=32;o>0;o>>=1){ s += __shfl_xor(s, o); s2 += __shfl_xor(s2, o); }
    float mean = s * (1.f/256.f);
    float var  = s2 * (1.f/256.f) - mean*mean;
    float inv  = rsqrtf(var + 1e-5f);
    float4 iv = *(const float4*)(in + (size_t)tok*HD + lane*4);
    float ivv[4] = {iv.x, iv.y, iv.z, iv.w};
    bf16x4 ov;
    #pragma unroll
    for (int j=0;j<4;++j){
        int c = lane*4 + j;
        float ln = (v[j]-mean)*inv*g[c] + bb[c];
        ov[j] = (bf16_t)(gelu_f(ln) + ivv[j]);
    }
    *(bf16x4*)(y + (size_t)tok*HD + lane*4) = ov;
}

// ---------------- head GEMM: out = y @ W + bias (fp32 out) ----------------
__global__ __launch_bounds__(256) void k_head(
    const bf16_t* __restrict__ A, const bf16_t* __restrict__ BT,
    const float* __restrict__ bias, float* __restrict__ out, int Nout)
{
    __shared__ bf16_t As[128][40];
    __shared__ bf16_t Bs[64][40];
    int row0 = blockIdx.x*128, col0 = blockIdx.y*64;
    int t = threadIdx.x, wave = t>>6, lane = t&63;
    int wm = wave>>1, wn = wave&1;
    f32x4 acc[4][2] = {};
    for (int k0=0; k0<HD; k0+=32){
        __syncthreads();
        #pragma unroll
        for (int u=0;u<2;++u){
            int fi = u*256 + t, r = fi>>2, q = fi&3;
            *(bf16x8*)(&As[r][q*8]) = *(const bf16x8*)(A + (size_t)(row0+r)*HD + k0 + q*8);
        }
        {
            int r = t>>2, q = t&3;
            *(bf16x8*)(&Bs[r][q*8]) = *(const bf16x8*)(BT + (size_t)(col0+r)*HD + k0 + q*8);
        }
        __syncthreads();
        int kq = lane>>4, lr = lane&15;
        bf16x8 af[4], bfr[2];
        #pragma unroll
        for (int m=0;m<4;++m) af[m] = *(const bf16x8*)(&As[wm*64 + m*16 + lr][kq*8]);
        #pragma unroll
        for (int n=0;n<2;++n) bfr[n] = *(const bf16x8*)(&Bs[wn*32 + n*16 + lr][kq*8]);
        #pragma unroll
        for (int m=0;m<4;++m)
            #pragma unroll
            for (int n=0;n<2;++n) acc[m][n] = mfma16(af[m], bfr[n], acc[m][n]);
    }
    int kq = lane>>4, lr = lane&15;
    #pragma unroll
    for (int n=0;n<2;++n){
        int col = col0 + wn*32 + n*16 + lr;
        float bv = bias[col];
        #pragma unroll
        for (int m=0;m<4;++m)
            #pragma unroll
            for (int r=0;r<4;++r){
                int row = row0 + wm*64 + m*16 + kq*4 + r;
                out[(size_t)row*Nout + col] = acc[m][n][r] + bv;
            }
    }
}

extern "C" void kernel_launch(void* const* d_in, const int* in_sizes, int n_in,
                              void* d_out, int out_size, void* d_ws, size_t ws_size,
                              hipStream_t stream)
{
    const float* x   = (const float*)d_in[0];
    const float* We  = (const float*)d_in[1];
    const float* be  = (const float*)d_in[2];
    const float* l2e = (const float*)d_in[3];
    const float* cle = (const float*)d_in[4];
    const float* gW  = (const float*)d_in[5];
    const float* gb  = (const float*)d_in[6];
    const float* W1  = (const float*)d_in[7];
    const float* b1  = (const float*)d_in[8];
    const float* W2  = (const float*)d_in[9];
    const float* b2  = (const float*)d_in[10];
    const float* l2g = (const float*)d_in[11];
    const float* l2b = (const float*)d_in[12];
    const float* clg = (const float*)d_in[13];
    const float* clb = (const float*)d_in[14];
    const float* Wt  = (const float*)d_in[15];
    const float* bt  = (const float*)d_in[16];
    const float* Wcl = (const float*)d_in[17];
    const float* bcl = (const float*)d_in[18];
    float* out = (float*)d_out;
    char* ws = (char*)d_ws;

    // workspace layout (bytes) — NEED 88523520
    const size_t O_META  = 0;
    const size_t O_TABLE = 256;        // 1040 * 16 = 16640 -> ends 16896
    const size_t O_TOPV  = 17152;
    const size_t O_TOPI  = 279296;
    const size_t O_POSOF = 541440;
    const size_t O_ROWS  = 803584;
    const size_t O_WEHI  = 1065728;
    const size_t O_W1T   = 1458944;
    const size_t O_W2T   = 2507520;
    const size_t O_WTT   = 3556096;
    const size_t O_WCLT  = 4080384;
    const size_t O_L2F   = 4211456;
    const size_t O_CLF   = 20988672;
    const size_t O_EO    = 37765888;
    const size_t O_L2H   = 71320320;   // bf16 acts; aliased by yl2 (written after moe)
    const size_t O_CLH   = 79708928;   // bf16 acts; aliased by ycl
    const size_t O_WELO  = 88097536;
    const size_t O_FLAG  = 88490752;   // 16384
    const size_t O_BASE  = 88507136;   // 8192
    const size_t O_BH    = 88515328;   // 8192
    const size_t NEED    = 88523520;
    if (ws_size < NEED) return;

    int*    meta    = (int*)(ws + O_META);
    int*    nflag   = meta + 48;
    int4*   table   = (int4*)(ws + O_TABLE);
    int*    blockhist = (int*)(ws + O_BH);
    float*  topv    = (float*)(ws + O_TOPV);
    int*    topi    = (int*)(ws + O_TOPI);
    int*    posof   = (int*)(ws + O_POSOF);
    int*    rows    = (int*)(ws + O_ROWS);
    bf16_t* WeHi    = (bf16_t*)(ws + O_WEHI);
    bf16_t* WeLo    = (bf16_t*)(ws + O_WELO);
    int*    flaglist= (int*)(ws + O_FLAG);
    int*    basep   = (int*)(ws + O_BASE);
    bf16_t* W1T     = (bf16_t*)(ws + O_W1T);
    bf16_t* W2T     = (bf16_t*)(ws + O_W2T);
    bf16_t* WtT     = (bf16_t*)(ws + O_WTT);
    bf16_t* WcT     = (bf16_t*)(ws + O_WCLT);
    float*  l2f     = (float*)(ws + O_L2F);
    float*  clf     = (float*)(ws + O_CLF);
    bf16_t* eo      = (bf16_t*)(ws + O_EO);
    bf16_t* l2h     = (bf16_t*)(ws + O_L2H);
    bf16_t* clh     = (bf16_t*)(ws + O_CLH);
    bf16_t* yl2     = (bf16_t*)(ws + O_L2H);   // alias: l2h dead after k_moe
    bf16_t* ycl     = (bf16_t*)(ws + O_CLH);   // alias: clh dead after k_moe

    k_zero<<<1, 64, 0, stream>>>(meta);
    k_convert<<<6144, 256, 0, stream>>>(We, W1, W2, Wt, Wcl, WeHi, WeLo, W1T, W2T, WtT, WcT);
    k_embed<<<dim3(128,4), 256, 0, stream>>>(x, WeHi, WeLo, be, l2e, cle, l2f, clf);
    k_gate<<<8192, 256, 0, stream>>>(l2f, clf, gW, gb, topv, topi, flaglist, nflag, l2h, clh);
    k_refine<<<256, 256, 0, stream>>>(x, We, be, l2e, cle, gW, gb, flaglist, nflag, topv, topi);
    k_hist<<<128, 256, 0, stream>>>(topi, blockhist);
    k_scan<<<1, 256, 0, stream>>>(blockhist, basep, table);
    k_scatter<<<128, 256, 0, stream>>>(topi, basep, rows, posof);
    k_moe<<<2*MOE_TPB, 512, 0, stream>>>(table, rows, l2h, clh, W1T, W2T, b1, b2, eo);
    k_combine<<<8192, 256, 0, stream>>>(eo, topv, posof, l2f, clf, l2g, l2b, clg, clb, yl2, ycl);
    k_head<<<dim3(128,16), 256, 0, stream>>>(yl2, WtT, bt, out, 1024);
    k_head<<<dim3(128,4), 256, 0, stream>>>(ycl, WcT, bcl, out + (size_t)16777216, 256);
}

// Round 9
// 217.201 us; speedup vs baseline: 1.3574x; 1.2320x over previous
//
#include <hip/hip_runtime.h>
#include <hip/hip_bf16.h>
#include <math.h>

typedef __bf16 bf16_t;
typedef __bf16 bf16x4 __attribute__((ext_vector_type(4)));
typedef __bf16 bf16x8 __attribute__((ext_vector_type(8)));
typedef float  f32x4  __attribute__((ext_vector_type(4)));

#define NTOK 16384   // B*S
#define HD   256     // hidden
#define TD   768
#define ID   1024
#define NPAIR 32768  // NTOK*2 per branch
#define MOE_TPB 520  // 64-row tiles per branch (512 + 8 boundary)
#define FLAG_CAP 4096

// fast erf: Abramowitz-Stegun 7.1.26, |err| <= 1.5e-7, branchless
__device__ inline float fast_erf(float x){
    float ax = fabsf(x);
    float t = 1.0f / (1.0f + 0.3275911f*ax);
    float y = t*(0.254829592f + t*(-0.284496736f + t*(1.421413741f +
              t*(-1.453152027f + t*1.061405429f))));
    float e = 1.0f - y*__expf(-ax*ax);
    return copysignf(e, x);
}
__device__ inline float gelu_f(float x){
    return 0.5f * x * (1.0f + fast_erf(x * 0.70710678118654752f));
}
__device__ inline bf16x4 cvt4(float4 a){
    bf16x4 o; o[0]=(bf16_t)a.x; o[1]=(bf16_t)a.y; o[2]=(bf16_t)a.z; o[3]=(bf16_t)a.w; return o;
}
__device__ inline f32x4 mfma16(bf16x8 a, bf16x8 b, f32x4 c){
    return __builtin_amdgcn_mfma_f32_16x16x32_bf16(a, b, c, 0, 0, 0);
}
// async global->LDS, 16B per lane; lds dest = wave-uniform base + lane*16
__device__ inline void gload_lds16(const void* g, void* l){
    __builtin_amdgcn_global_load_lds(
        (const __attribute__((address_space(1))) unsigned int*)g,
        (__attribute__((address_space(3))) unsigned int*)l, 16, 0, 0);
}

// ---------------- zero meta ----------------
__global__ void k_zero(int* meta){
    if (threadIdx.x < 64) meta[threadIdx.x] = 0;   // nflag@48
}

// ---------------- weight convert: coalesced 64x64 LDS-tile transpose ----------------
__global__ __launch_bounds__(256) void k_convert(
    const float* __restrict__ We, const float* __restrict__ W1,
    const float* __restrict__ W2, const float* __restrict__ Wt,
    const float* __restrict__ Wc,
    bf16_t* __restrict__ WeHi, bf16_t* __restrict__ WeLo,
    bf16_t* __restrict__ W1T,
    bf16_t* __restrict__ W2T, bf16_t* __restrict__ WtT, bf16_t* __restrict__ WcT)
{
    __shared__ float T[64][65];
    int job = blockIdx.x;
    const float* src; bf16_t* dst; bf16_t* dst2 = nullptr;
    int K, N, k0, n0;   // src [K][N] -> dst [N][K]
    if (job < 48){ src = We;  dst = WeHi; dst2 = WeLo; K = 768; N = 256;
        k0 = (job>>2)*64; n0 = (job&3)*64;
    } else if (job < 176){ int e = (job-48)>>4, tj = (job-48)&15;
        src = W1 + ((size_t)e<<16); dst = W1T + ((size_t)e<<16); K=256; N=256;
        k0 = (tj>>2)*64; n0 = (tj&3)*64;
    } else if (job < 304){ int e = (job-176)>>4, tj = (job-176)&15;
        src = W2 + ((size_t)e<<16); dst = W2T + ((size_t)e<<16); K=256; N=256;
        k0 = (tj>>2)*64; n0 = (tj&3)*64;
    } else if (job < 368){ int tj = job-304; src = Wt; dst = WtT; K=256; N=1024;
        k0 = (tj>>4)*64; n0 = (tj&15)*64;
    } else { int tj = job-368; src = Wc; dst = WcT; K=256; N=256;
        k0 = (tj>>2)*64; n0 = (tj&3)*64;
    }
    int t = threadIdx.x;
    #pragma unroll
    for (int u=0;u<4;++u){
        int unit = u*256 + t;            // 0..1023
        int r = unit>>4, c4 = (unit&15)*4;
        float4 v = *(const float4*)(src + (size_t)(k0+r)*N + n0 + c4);
        T[r][c4] = v.x; T[r][c4+1] = v.y; T[r][c4+2] = v.z; T[r][c4+3] = v.w;
    }
    __syncthreads();
    #pragma unroll
    for (int u=0;u<4;++u){
        int unit = u*256 + t;
        int rn = unit>>4, c4 = (unit&15)*4;   // rn: n in tile; c4: k chunk
        bf16x4 h, l;
        #pragma unroll
        for (int j=0;j<4;++j){
            float f = T[c4+j][rn];
            bf16_t hb = (bf16_t)f;
            h[j] = hb; l[j] = (bf16_t)(f - (float)hb);
        }
        *(bf16x4*)(dst + (size_t)(n0+rn)*K + k0 + c4) = h;
        if (dst2) *(bf16x4*)(dst2 + (size_t)(n0+rn)*K + k0 + c4) = l;
    }
}

// ---------------- embed (split-bf16, 3-pass): X = gelu(x@We+be); l2f/clf fp32 only ----------------
__global__ __launch_bounds__(256) void k_embed(
    const float* __restrict__ x, const bf16_t* __restrict__ WeHi,
    const bf16_t* __restrict__ WeLo,
    const float* __restrict__ be, const float* __restrict__ l2e,
    const float* __restrict__ cle,
    float* __restrict__ l2f, float* __restrict__ clf)
{
    __shared__ bf16_t Ah[128][40];
    __shared__ bf16_t Al[128][40];
    __shared__ bf16_t Bh[64][40];
    __shared__ bf16_t Bl[64][40];
    int row0 = blockIdx.x*128, col0 = blockIdx.y*64;
    int t = threadIdx.x, wave = t>>6, lane = t&63;
    int wm = wave>>1, wn = wave&1;
    f32x4 acc[4][2] = {};
    for (int k0 = 0; k0 < TD; k0 += 32){
        __syncthreads();
        #pragma unroll
        for (int u=0; u<4; ++u){
            int fi = u*256 + t, r = fi>>3, q = fi&7;
            float4 v = *(const float4*)(x + (size_t)(row0+r)*TD + k0 + q*4);
            bf16x4 h = cvt4(v);
            float4 rl;
            rl.x = v.x-(float)h[0]; rl.y = v.y-(float)h[1];
            rl.z = v.z-(float)h[2]; rl.w = v.w-(float)h[3];
            *(bf16x4*)(&Ah[r][q*4]) = h;
            *(bf16x4*)(&Al[r][q*4]) = cvt4(rl);
        }
        {
            int r = t>>2, q = t&3;
            *(bf16x8*)(&Bh[r][q*8]) = *(const bf16x8*)(WeHi + (size_t)(col0+r)*TD + k0 + q*8);
            *(bf16x8*)(&Bl[r][q*8]) = *(const bf16x8*)(WeLo + (size_t)(col0+r)*TD + k0 + q*8);
        }
        __syncthreads();
        int kq = lane>>4, lr = lane&15;
        bf16x8 ah[4], al[4], bh[2], bl[2];
        #pragma unroll
        for (int m=0;m<4;++m){
            ah[m] = *(const bf16x8*)(&Ah[wm*64 + m*16 + lr][kq*8]);
            al[m] = *(const bf16x8*)(&Al[wm*64 + m*16 + lr][kq*8]);
        }
        #pragma unroll
        for (int n=0;n<2;++n){
            bh[n] = *(const bf16x8*)(&Bh[wn*32 + n*16 + lr][kq*8]);
            bl[n] = *(const bf16x8*)(&Bl[wn*32 + n*16 + lr][kq*8]);
        }
        #pragma unroll
        for (int m=0;m<4;++m)
            #pragma unroll
            for (int n=0;n<2;++n){
                acc[m][n] = mfma16(ah[m], bh[n], acc[m][n]);
                acc[m][n] = mfma16(ah[m], bl[n], acc[m][n]);
                acc[m][n] = mfma16(al[m], bh[n], acc[m][n]);
            }
    }
    int kq = lane>>4, lr = lane&15;
    #pragma unroll
    for (int n=0;n<2;++n){
        int col = col0 + wn*32 + n*16 + lr;
        float bv = be[col], lv = l2e[col], cv = cle[col];
        #pragma unroll
        for (int m=0;m<4;++m)
            #pragma unroll
            for (int r=0;r<4;++r){
                int row = row0 + wm*64 + m*16 + kq*4 + r;
                float v = gelu_f(acc[m][n][r] + bv);
                l2f[(size_t)row*HD + col] = v + lv;
                clf[(size_t)row*HD + col] = v + cv;
            }
    }
}

// ---------------- gate: softmax + top2 + near-tie flags + bf16 activation emit ----------------
__global__ __launch_bounds__(256) void k_gate(
    const float* __restrict__ l2f, const float* __restrict__ clf,
    const float* __restrict__ gW, const float* __restrict__ gb,
    float* __restrict__ topv, int* __restrict__ topi,
    int* __restrict__ flaglist, int* __restrict__ nflag,
    bf16_t* __restrict__ l2h, bf16_t* __restrict__ clh)
{
    __shared__ float gw[2048];
    int t = threadIdx.x;
    for (int i=t; i<2048; i+=256) gw[i] = gW[i];
    __syncthreads();
    int wave = t>>6, lane = t&63;
    int idx = blockIdx.x*4 + wave;
    int br = idx>>14, tok = idx&16383;
    const float* in = br ? clf : l2f;
    float4 v = *(const float4*)(in + (size_t)tok*HD + lane*4);
    float xv[4] = {v.x, v.y, v.z, v.w};
    {
        bf16x4 hv; hv[0]=(bf16_t)v.x; hv[1]=(bf16_t)v.y; hv[2]=(bf16_t)v.z; hv[3]=(bf16_t)v.w;
        bf16_t* hout = br ? clh : l2h;
        *(bf16x4*)(hout + (size_t)tok*HD + lane*4) = hv;
    }
    float p[8];
    #pragma unroll
    for (int e=0;e<8;++e) p[e] = 0.f;
    #pragma unroll
    for (int j=0;j<4;++j){
        const float* g = &gw[(lane*4+j)*8];
        #pragma unroll
        for (int e=0;e<8;++e) p[e] += xv[j]*g[e];
    }
    #pragma unroll
    for (int e=0;e<8;++e){
        float s = p[e];
        #pragma unroll
        for (int o=32;o>0;o>>=1) s += __shfl_xor(s, o);
        p[e] = s + gb[e];
    }
    float mx = p[0];
    #pragma unroll
    for (int e=1;e<8;++e) mx = fmaxf(mx, p[e]);
    float den = 0.f;
    #pragma unroll
    for (int e=0;e<8;++e) den += expf(p[e]-mx);
    int i1 = 0; float m1 = p[0];
    #pragma unroll
    for (int e=1;e<8;++e) if (p[e] > m1){ m1 = p[e]; i1 = e; }
    int i2 = (i1==0)?1:0; float m2 = p[i2];
    #pragma unroll
    for (int e=0;e<8;++e) if (e != i1 && p[e] > m2){ m2 = p[e]; i2 = e; }
    if (lane == 0){
        topv[idx*2]   = expf(m1-mx)/den;
        topv[idx*2+1] = expf(m2-mx)/den;
        topi[idx*2]   = i1;
        topi[idx*2+1] = i2;
        float m3 = -1e30f;
        #pragma unroll
        for (int e=0;e<8;++e) if (e != i1 && e != i2) m3 = fmaxf(m3, p[e]);
        if (m2 - m3 < 1e-3f){
            int slot = atomicAdd(nflag, 1);
            if (slot < FLAG_CAP) flaglist[slot] = idx;
        }
    }
}

// ---------------- refine: exact f64 gating for near-tie tokens ----------------
__global__ __launch_bounds__(256) void k_refine(
    const float* __restrict__ x, const float* __restrict__ We,
    const float* __restrict__ be,
    const float* __restrict__ l2e, const float* __restrict__ cle,
    const float* __restrict__ gW, const float* __restrict__ gb,
    const int* __restrict__ flaglist, const int* __restrict__ nflag,
    float* __restrict__ topv, int* __restrict__ topi)
{
    __shared__ float xs[768];
    __shared__ double red[256][8];
    int t = threadIdx.x;
    int nf = *nflag; if (nf > FLAG_CAP) nf = FLAG_CAP;
    for (int f = blockIdx.x; f < nf; f += gridDim.x){
        int idx = flaglist[f];
        int br = idx>>14, tok = idx&16383;
        __syncthreads();
        for (int i=t; i<768; i+=256) xs[i] = x[(size_t)tok*768 + i];
        __syncthreads();
        double u = 0.0;
        for (int j=0;j<768;++j) u += (double)xs[j] * (double)We[(size_t)j*256 + t];
        u += (double)be[t];
        double act = 0.5*u*(1.0 + erf(u*0.70710678118654752440));
        double li = act + (double)(br ? cle[t] : l2e[t]);
        #pragma unroll
        for (int e=0;e<8;++e) red[t][e] = li * (double)gW[t*8+e];
        __syncthreads();
        for (int s=128; s>0; s>>=1){
            if (t < s){
                #pragma unroll
                for (int e=0;e<8;++e) red[t][e] += red[t+s][e];
            }
            __syncthreads();
        }
        if (t == 0){
            double p[8];
            #pragma unroll
            for (int e=0;e<8;++e) p[e] = red[0][e] + (double)gb[e];
            int i1 = 0; double m1 = p[0];
            #pragma unroll
            for (int e=1;e<8;++e) if (p[e] > m1){ m1 = p[e]; i1 = e; }
            int i2 = (i1==0)?1:0; double m2 = p[i2];
            #pragma unroll
            for (int e=0;e<8;++e) if (e != i1 && p[e] > m2){ m2 = p[e]; i2 = e; }
            double mx = m1, den = 0.0;
            #pragma unroll
            for (int e=0;e<8;++e) den += exp(p[e]-mx);
            topv[idx*2]   = (float)(exp(m1-mx)/den);
            topv[idx*2+1] = (float)(exp(m2-mx)/den);
            topi[idx*2]   = i1;
            topi[idx*2+1] = i2;
        }
    }
}

// ---------------- per-block histogram (LDS atomics only) ----------------
__global__ __launch_bounds__(256) void k_hist(
    const int* __restrict__ topi, int* __restrict__ blockhist)
{
    __shared__ int h[16];
    int t = threadIdx.x;
    if (t < 16) h[t] = 0;
    __syncthreads();
    int idx = blockIdx.x*256 + t;
    int br = idx>>14;
    atomicAdd(&h[br*8 + topi[idx*2]], 1);
    atomicAdd(&h[br*8 + topi[idx*2+1]], 1);
    __syncthreads();
    if (t < 16) blockhist[blockIdx.x*16 + t] = h[t];
}

// ---------------- scan: per-block bases + expert offsets + 64-row tile table ----------------
__global__ void k_scan(const int* __restrict__ blockhist, int* __restrict__ base,
                       int4* __restrict__ table)
{
    __shared__ int tot[16], off[16], tpre[2][9];
    int t = threadIdx.x;
    if (t < 16){
        int s = 0;
        for (int b=0;b<128;++b){ base[b*16+t] = s; s += blockhist[b*16+t]; }
        tot[t] = s;
    }
    __syncthreads();
    if (t == 0){
        for (int br=0;br<2;++br){
            int s=0, tp=0; tpre[br][0]=0;
            for (int e=0;e<8;++e){
                off[br*8+e]=s; s += tot[br*8+e];
                tp += (tot[br*8+e]+63)>>6; tpre[br][e+1]=tp;
            }
        }
    }
    __syncthreads();
    for (int i=t; i<2048; i+=256) base[i] += off[i&15];
    for (int i=t; i<2*MOE_TPB; i+=256){
        int b = i/MOE_TPB, ti = i%MOE_TPB;
        int4 ent = make_int4(-1,0,0,0);
        if (ti < tpre[b][8]){
            int e = 0;
            while (ti >= tpre[b][e+1]) ++e;
            int k = ti - tpre[b][e];
            int s = off[b*8+e] + k*64;
            int en = off[b*8+e] + tot[b*8+e];
            ent = make_int4(e, s, (s+64 < en) ? (s+64) : en, b);
        }
        table[i] = ent;
    }
}

// ---------------- scatter: LDS-local ranks + per-block base ----------------
__global__ __launch_bounds__(256) void k_scatter(
    const int* __restrict__ topi, const int* __restrict__ base,
    int* __restrict__ rows, int* __restrict__ posof)
{
    __shared__ int h[16];
    int t = threadIdx.x;
    if (t < 16) h[t] = 0;
    __syncthreads();
    int idx = blockIdx.x*256 + t;
    int br = idx>>14, tok = idx&16383;
    int e0 = topi[idx*2], e1 = topi[idx*2+1];
    int r0 = atomicAdd(&h[br*8+e0], 1);
    int r1 = atomicAdd(&h[br*8+e1], 1);
    int p0 = base[blockIdx.x*16 + br*8 + e0] + r0;
    int p1 = base[blockIdx.x*16 + br*8 + e1] + r1;
    rows[br*NPAIR + p0] = tok;
    rows[br*NPAIR + p1] = tok;
    posof[idx*2]   = p0;
    posof[idx*2+1] = p1;
}

// ---------------- grouped MoE: all MFMA operands via global_load_lds + ds_read (m97 style) ----------------
__global__ __launch_bounds__(512, 4) void k_moe(
    const int4* __restrict__ table, const int* __restrict__ rows,
    const bf16_t* __restrict__ l2h, const bf16_t* __restrict__ clh,
    const bf16_t* __restrict__ W1T, const bf16_t* __restrict__ W2T,
    const float* __restrict__ b1, const float* __restrict__ b2,
    bf16_t* __restrict__ eo)
{
    int4 te = table[blockIdx.x];
    int e = te.x, start = te.y, end = te.z, br = te.w;
    if (e < 0) return;
    const bf16_t* inb = br ? clh : l2h;

    __shared__ bf16_t Ab[64*256];   // 32KB: A-tile, then h-tile (16B-chunk XOR row&7)
    __shared__ bf16_t Bb[256*64];   // 32KB: one BK=64 weight step (16B-chunk XOR row&7)
    char* ab = (char*)Ab;
    char* bb = (char*)Bb;

    int t = threadIdx.x, w = t>>6, lane = t&63;
    int wm = w>>2, wn = w&3;          // wave: rows wm*32.., cols wn*64..
    int kq = lane>>4, lr = lane&15;

    // ---- stage A tile (64 rows x 256K), swizzled source, linear dest ----
    #pragma unroll
    for (int u=0; u<4; ++u){
        int unit = (w*4+u)*64 + lane;         // 0..2047
        int row = unit>>5, ch = unit&31;
        int pos = start + row;
        int tok = rows[br*NPAIR + ((pos < end) ? pos : start)];
        gload_lds16(inb + (size_t)tok*HD + ((ch ^ (row&7))<<3), ab + (w*4+u)*1024);
    }
    const bf16_t* W1e = W1T + ((size_t)e<<16);
    const bf16_t* W2e = W2T + ((size_t)e<<16);
    // ---- stage B step 0 (256 ncol x 64K) ----
    #pragma unroll
    for (int u=0; u<4; ++u){
        int unit = (w*4+u)*64 + lane;         // 0..2047
        int row = unit>>3, c = unit&7;
        gload_lds16(W1e + (size_t)row*HD + ((c ^ (row&7))<<3), bb + (w*4+u)*1024);
    }
    __syncthreads();                           // drains both stages

    f32x4 acc[2][4] = {};
    // ---- GEMM1: 4 BK=64 steps ----
    for (int s=0; s<4; ++s){
        #pragma unroll
        for (int kk=0; kk<2; ++kk){
            bf16x8 af[2], bfr[4];
            #pragma unroll
            for (int m=0;m<2;++m){
                int row = wm*32 + m*16 + lr;
                int ch = s*8 + kk*4 + kq;
                af[m] = *(const bf16x8*)(ab + row*512 + ((ch ^ (row&7))<<4));
            }
            #pragma unroll
            for (int n=0;n<4;++n){
                int nc = wn*64 + n*16 + lr;
                int c = kk*4 + kq;
                bfr[n] = *(const bf16x8*)(bb + nc*128 + ((c ^ (nc&7))<<4));
            }
            #pragma unroll
            for (int m=0;m<2;++m)
                #pragma unroll
                for (int n=0;n<4;++n) acc[m][n] = mfma16(af[m], bfr[n], acc[m][n]);
        }
        __syncthreads();                       // everyone done reading Bb (and Ab at s=3)
        if (s < 3){
            #pragma unroll
            for (int u=0; u<4; ++u){
                int unit = (w*4+u)*64 + lane;
                int row = unit>>3, c = unit&7;
                gload_lds16(W1e + (size_t)row*HD + (s+1)*64 + ((c ^ (row&7))<<3),
                            bb + (w*4+u)*1024);
            }
            __syncthreads();                   // landed
        }
    }
    // ---- issue W2 step-0 stage now (Bb free); overlaps h epilogue ----
    #pragma unroll
    for (int u=0; u<4; ++u){
        int unit = (w*4+u)*64 + lane;
        int row = unit>>3, c = unit&7;
        gload_lds16(W2e + (size_t)row*HD + ((c ^ (row&7))<<3), bb + (w*4+u)*1024);
    }
    // ---- h = gelu(acc + b1) -> Ab (A consumed) ----
    #pragma unroll
    for (int n=0;n<4;++n){
        int col = wn*64 + n*16 + lr;
        float bv = b1[e*256 + col];
        #pragma unroll
        for (int m=0;m<2;++m)
            #pragma unroll
            for (int r=0;r<4;++r){
                int row = wm*32 + m*16 + kq*4 + r;
                int byte = row*512 + ((((col>>3) ^ (row&7))<<4)) + (col&7)*2;
                *(bf16_t*)(ab + byte) = (bf16_t)gelu_f(acc[m][n][r] + bv);
            }
    }
    __syncthreads();                           // drains W2 stage + h writes
    // ---- GEMM2: 4 BK=64 steps; h from Ab ----
    #pragma unroll
    for (int m=0;m<2;++m)
        #pragma unroll
        for (int n=0;n<4;++n)
            #pragma unroll
            for (int r=0;r<4;++r) acc[m][n][r] = 0.f;
    for (int s=0; s<4; ++s){
        #pragma unroll
        for (int kk=0; kk<2; ++kk){
            bf16x8 af[2], bfr[4];
            #pragma unroll
            for (int m=0;m<2;++m){
                int row = wm*32 + m*16 + lr;
                int ch = s*8 + kk*4 + kq;
                af[m] = *(const bf16x8*)(ab + row*512 + ((ch ^ (row&7))<<4));
            }
            #pragma unroll
            for (int n=0;n<4;++n){
                int nc = wn*64 + n*16 + lr;
                int c = kk*4 + kq;
                bfr[n] = *(const bf16x8*)(bb + nc*128 + ((c ^ (nc&7))<<4));
            }
            #pragma unroll
            for (int m=0;m<2;++m)
                #pragma unroll
                for (int n=0;n<4;++n) acc[m][n] = mfma16(af[m], bfr[n], acc[m][n]);
        }
        if (s < 3){
            __syncthreads();
            #pragma unroll
            for (int u=0; u<4; ++u){
                int unit = (w*4+u)*64 + lane;
                int row = unit>>3, c = unit&7;
                gload_lds16(W2e + (size_t)row*HD + (s+1)*64 + ((c ^ (row&7))<<3),
                            bb + (w*4+u)*1024);
            }
            __syncthreads();
        }
    }
    // ---- eo = acc + b2, scattered per-lane stores ----
    #pragma unroll
    for (int n=0;n<4;++n){
        int col = wn*64 + n*16 + lr;
        float bv = b2[e*256 + col];
        #pragma unroll
        for (int m=0;m<2;++m)
            #pragma unroll
            for (int r=0;r<4;++r){
                int pos = start + wm*32 + m*16 + kq*4 + r;
                if (pos < end)
                    eo[((size_t)br*NPAIR + pos)*HD + col] = (bf16_t)(acc[m][n][r] + bv);
            }
    }
}

// ---------------- combine + LN + gelu + residual -> y (bf16) ----------------
__global__ __launch_bounds__(256) void k_combine(
    const bf16_t* __restrict__ eo, const float* __restrict__ topv,
    const int* __restrict__ posof,
    const float* __restrict__ l2f, const float* __restrict__ clf,
    const float* __restrict__ l2g, const float* __restrict__ l2b,
    const float* __restrict__ clg, const float* __restrict__ clb,
    bf16_t* __restrict__ yl2, bf16_t* __restrict__ ycl)
{
    int t = threadIdx.x, wave = t>>6, lane = t&63;
    int idx = blockIdx.x*4 + wave;
    int br = idx>>14, tok = idx&16383;
    const float* in = br ? clf : l2f;
    const float* g  = br ? clg : l2g;
    const float* bb = br ? clb : l2b;
    bf16_t* y = br ? ycl : yl2;
    int p0 = posof[idx*2], p1 = posof[idx*2+1];
    float w0 = topv[idx*2], w1 = topv[idx*2+1];
    bf16x4 e0 = *(const bf16x4*)(eo + ((size_t)br*NPAIR + p0)*HD + lane*4);
    bf16x4 e1 = *(const bf16x4*)(eo + ((size_t)br*NPAIR + p1)*HD + lane*4);
    float v[4], s = 0.f, s2 = 0.f;
    #pragma unroll
    for (int j=0;j<4;++j){
        v[j] = w0*(float)e0[j] + w1*(float)e1[j];
        s += v[j]; s2 += v[j]*v[j];
    }
    #pragma unroll
    for (int o=32;o>0;o>>=1){ s += __shfl_xor(s, o); s2 += __shfl_xor(s2, o); }
    float mean = s * (1.f/256.f);
    float var  = s2 * (1.f/256.f) - mean*mean;
    float inv  = rsqrtf(var + 1e-5f);
    float4 iv = *(const float4*)(in + (size_t)tok*HD + lane*4);
    float ivv[4] = {iv.x, iv.y, iv.z, iv.w};
    bf16x4 ov;
    #pragma unroll
    for (int j=0;j<4;++j){
        int c = lane*4 + j;
        float ln = (v[j]-mean)*inv*g[c] + bb[c];
        ov[j] = (bf16_t)(gelu_f(ln) + ivv[j]);
    }
    *(bf16x4*)(y + (size_t)tok*HD + lane*4) = ov;
}

// ---------------- head GEMM: out = y @ W + bias (fp32 out) ----------------
__global__ __launch_bounds__(256) void k_head(
    const bf16_t* __restrict__ A, const bf16_t* __restrict__ BT,
    const float* __restrict__ bias, float* __restrict__ out, int Nout)
{
    __shared__ bf16_t As[128][40];
    __shared__ bf16_t Bs[64][40];
    int row0 = blockIdx.x*128, col0 = blockIdx.y*64;
    int t = threadIdx.x, wave = t>>6, lane = t&63;
    int wm = wave>>1, wn = wave&1;
    f32x4 acc[4][2] = {};
    for (int k0=0; k0<HD; k0+=32){
        __syncthreads();
        #pragma unroll
        for (int u=0;u<2;++u){
            int fi = u*256 + t, r = fi>>2, q = fi&3;
            *(bf16x8*)(&As[r][q*8]) = *(const bf16x8*)(A + (size_t)(row0+r)*HD + k0 + q*8);
        }
        {
            int r = t>>2, q = t&3;
            *(bf16x8*)(&Bs[r][q*8]) = *(const bf16x8*)(BT + (size_t)(col0+r)*HD + k0 + q*8);
        }
        __syncthreads();
        int kq = lane>>4, lr = lane&15;
        bf16x8 af[4], bfr[2];
        #pragma unroll
        for (int m=0;m<4;++m) af[m] = *(const bf16x8*)(&As[wm*64 + m*16 + lr][kq*8]);
        #pragma unroll
        for (int n=0;n<2;++n) bfr[n] = *(const bf16x8*)(&Bs[wn*32 + n*16 + lr][kq*8]);
        #pragma unroll
        for (int m=0;m<4;++m)
            #pragma unroll
            for (int n=0;n<2;++n) acc[m][n] = mfma16(af[m], bfr[n], acc[m][n]);
    }
    int kq = lane>>4, lr = lane&15;
    #pragma unroll
    for (int n=0;n<2;++n){
        int col = col0 + wn*32 + n*16 + lr;
        float bv = bias[col];
        #pragma unroll
        for (int m=0;m<4;++m)
            #pragma unroll
            for (int r=0;r<4;++r){
                int row = row0 + wm*64 + m*16 + kq*4 + r;
                out[(size_t)row*Nout + col] = acc[m][n][r] + bv;
            }
    }
}

extern "C" void kernel_launch(void* const* d_in, const int* in_sizes, int n_in,
                              void* d_out, int out_size, void* d_ws, size_t ws_size,
                              hipStream_t stream)
{
    const float* x   = (const float*)d_in[0];
    const float* We  = (const float*)d_in[1];
    const float* be  = (const float*)d_in[2];
    const float* l2e = (const float*)d_in[3];
    const float* cle = (const float*)d_in[4];
    const float* gW  = (const float*)d_in[5];
    const float* gb  = (const float*)d_in[6];
    const float* W1  = (const float*)d_in[7];
    const float* b1  = (const float*)d_in[8];
    const float* W2  = (const float*)d_in[9];
    const float* b2  = (const float*)d_in[10];
    const float* l2g = (const float*)d_in[11];
    const float* l2b = (const float*)d_in[12];
    const float* clg = (const float*)d_in[13];
    const float* clb = (const float*)d_in[14];
    const float* Wt  = (const float*)d_in[15];
    const float* bt  = (const float*)d_in[16];
    const float* Wcl = (const float*)d_in[17];
    const float* bcl = (const float*)d_in[18];
    float* out = (float*)d_out;
    char* ws = (char*)d_ws;

    // workspace layout (bytes) — NEED 88523520
    const size_t O_META  = 0;
    const size_t O_TABLE = 256;        // 1040 * 16 = 16640 -> ends 16896
    const size_t O_TOPV  = 17152;
    const size_t O_TOPI  = 279296;
    const size_t O_POSOF = 541440;
    const size_t O_ROWS  = 803584;
    const size_t O_WEHI  = 1065728;
    const size_t O_W1T   = 1458944;
    const size_t O_W2T   = 2507520;
    const size_t O_WTT   = 3556096;
    const size_t O_WCLT  = 4080384;
    const size_t O_L2F   = 4211456;
    const size_t O_CLF   = 20988672;
    const size_t O_EO    = 37765888;
    const size_t O_L2H   = 71320320;   // bf16 acts; aliased by yl2 (written after moe)
    const size_t O_CLH   = 79708928;   // bf16 acts; aliased by ycl
    const size_t O_WELO  = 88097536;
    const size_t O_FLAG  = 88490752;   // 16384
    const size_t O_BASE  = 88507136;   // 8192
    const size_t O_BH    = 88515328;   // 8192
    const size_t NEED    = 88523520;
    if (ws_size < NEED) return;

    int*    meta    = (int*)(ws + O_META);
    int*    nflag   = meta + 48;
    int4*   table   = (int4*)(ws + O_TABLE);
    int*    blockhist = (int*)(ws + O_BH);
    float*  topv    = (float*)(ws + O_TOPV);
    int*    topi    = (int*)(ws + O_TOPI);
    int*    posof   = (int*)(ws + O_POSOF);
    int*    rows    = (int*)(ws + O_ROWS);
    bf16_t* WeHi    = (bf16_t*)(ws + O_WEHI);
    bf16_t* WeLo    = (bf16_t*)(ws + O_WELO);
    int*    flaglist= (int*)(ws + O_FLAG);
    int*    basep   = (int*)(ws + O_BASE);
    bf16_t* W1T     = (bf16_t*)(ws + O_W1T);
    bf16_t* W2T     = (bf16_t*)(ws + O_W2T);
    bf16_t* WtT     = (bf16_t*)(ws + O_WTT);
    bf16_t* WcT     = (bf16_t*)(ws + O_WCLT);
    float*  l2f     = (float*)(ws + O_L2F);
    float*  clf     = (float*)(ws + O_CLF);
    bf16_t* eo      = (bf16_t*)(ws + O_EO);
    bf16_t* l2h     = (bf16_t*)(ws + O_L2H);
    bf16_t* clh     = (bf16_t*)(ws + O_CLH);
    bf16_t* yl2     = (bf16_t*)(ws + O_L2H);   // alias: l2h dead after k_moe
    bf16_t* ycl     = (bf16_t*)(ws + O_CLH);   // alias: clh dead after k_moe

    k_zero<<<1, 64, 0, stream>>>(meta);
    k_convert<<<384, 256, 0, stream>>>(We, W1, W2, Wt, Wcl, WeHi, WeLo, W1T, W2T, WtT, WcT);
    k_embed<<<dim3(128,4), 256, 0, stream>>>(x, WeHi, WeLo, be, l2e, cle, l2f, clf);
    k_gate<<<8192, 256, 0, stream>>>(l2f, clf, gW, gb, topv, topi, flaglist, nflag, l2h, clh);
    k_refine<<<256, 256, 0, stream>>>(x, We, be, l2e, cle, gW, gb, flaglist, nflag, topv, topi);
    k_hist<<<128, 256, 0, stream>>>(topi, blockhist);
    k_scan<<<1, 256, 0, stream>>>(blockhist, basep, table);
    k_scatter<<<128, 256, 0, stream>>>(topi, basep, rows, posof);
    k_moe<<<2*MOE_TPB, 512, 0, stream>>>(table, rows, l2h, clh, W1T, W2T, b1, b2, eo);
    k_combine<<<8192, 256, 0, stream>>>(eo, topv, posof, l2f, clf, l2g, l2b, clg, clb, yl2, ycl);
    k_head<<<dim3(128,16), 256, 0, stream>>>(yl2, WtT, bt, out, 1024);
    k_head<<<dim3(128,4), 256, 0, stream>>>(ycl, WcT, bcl, out + (size_t)16777216, 256);
}